// Round 18
// baseline (373.014 us; speedup 1.0000x reference)
//
#include <hip/hip_runtime.h>
#include <hip/hip_bf16.h>

#define DM 1024
#define S_LEN 2048
#define NH 16
#define DEPTH 64
#define BATCH 2
#define LOG2E 1.4426950408889634f

typedef float f32x4 __attribute__((ext_vector_type(4)));
typedef __bf16 bf16x8 __attribute__((ext_vector_type(8)));
typedef unsigned short us8 __attribute__((ext_vector_type(8)));
typedef unsigned short us4 __attribute__((ext_vector_type(4)));

__device__ __forceinline__ unsigned short b16(float f) {
  return __builtin_bit_cast(unsigned short, (__bf16)f);
}
__device__ __forceinline__ float ex2(float x) {
#if __has_builtin(__builtin_amdgcn_exp2f)
  return __builtin_amdgcn_exp2f(x);
#else
  return exp2f(x);
#endif
}
__device__ __forceinline__ f32x4 mfma16(us8 a, us8 b, f32x4 c) {
  return __builtin_amdgcn_mfma_f32_16x16x32_bf16(
      __builtin_bit_cast(bf16x8, a), __builtin_bit_cast(bf16x8, b), c, 0, 0, 0);
}
// async global->LDS, 16B per lane; LDS dest = wave-uniform base (+lane*16 by HW)
__device__ __forceinline__ void gll16(const void* g, void* l) {
  __builtin_amdgcn_global_load_lds(
      (const __attribute__((address_space(1))) void*)g,
      (__attribute__((address_space(3))) void*)l, 16, 0, 0);
}
// swizzled LDS read: 16B chunk c of row r lives at slot c^(r&7); rows are 128B
#define SWZ_RD(baseB, r, c) \
  (*(const us8*)((baseB) + (size_t)(r) * 128 + ((((c) ^ ((r) & 7))) << 4)))

// stage a 128-row x 128B tile (global rows r0.., row stride RSB bytes) into LDS
// dst, inverse-swizzled source so SWZ_RD sees chunk^(row&7). 4 gll16/thread.
template <int RSB>
__device__ __forceinline__ void stage128(const char* Gb, int r0, int kb,
                                         char* dst, int tid) {
#pragma unroll
  for (int i = 0; i < 4; i++) {
    int t16 = i * 256 + tid;
    int row = t16 >> 3;
    int g = (t16 & 7) ^ (row & 7);
    gll16(Gb + (size_t)(r0 + row) * RSB + kb + (g << 4),
          dst + i * 4096 + (tid & ~63) * 16);
  }
}

// 64-row x 128B tile (row stride 2048B): 2 gll16/thread = 8 KB.
__device__ __forceinline__ void stage64a(const char* Gb, int r0, int kb,
                                         char* dst, int tid) {
#pragma unroll
  for (int i = 0; i < 2; i++) {
    int t16 = i * 256 + tid;
    int row = t16 >> 3;
    int g = (t16 & 7) ^ (row & 7);
    gll16(Gb + (size_t)(r0 + row) * 2048 + kb + (g << 4),
          dst + i * 4096 + (tid & ~63) * 16);
  }
}

// K staging (128 rows) with per-32-row-block sigma permutation: LDS row i holds
// key sigma(i) so QK^T's C/D lane mapping directly yields PV A-fragment key
// order (keys 8*lh..8*lh+7 per lane).
__device__ __forceinline__ void stage128k(const char* Gb, int r0, char* dst,
                                          int tid) {
#pragma unroll
  for (int i = 0; i < 4; i++) {
    int t16 = i * 256 + tid;
    int row = t16 >> 3;
    int g = (t16 & 7) ^ (row & 7);
    int i5 = row & 31, jj = i5 & 15, hi = i5 >> 4;
    int prow = (row & 96) | ((jj >> 2) << 3) | (hi << 2) | (jj & 3);
    gll16(Gb + (size_t)(r0 + prow) * 128 + (g << 4),
          dst + i * 4096 + (tid & ~63) * 16);
  }
}

// ---------------- f32 -> bf16 convert for q/k/v activations ----------------
__global__ __launch_bounds__(256) void cvt3_k(const float* __restrict__ q,
    const float* __restrict__ k, const float* __restrict__ v,
    unsigned short* __restrict__ oq, unsigned short* __restrict__ ok,
    unsigned short* __restrict__ ov) {
  const float* src = blockIdx.y == 0 ? q : blockIdx.y == 1 ? k : v;
  unsigned short* dst = blockIdx.y == 0 ? oq : blockIdx.y == 1 ? ok : ov;
  size_t i = ((size_t)blockIdx.x * 256 + threadIdx.x) * 8;
  float4 f0 = *(const float4*)(src + i);
  float4 f1 = *(const float4*)(src + i + 4);
  us8 o;
  o[0] = b16(f0.x); o[1] = b16(f0.y); o[2] = b16(f0.z); o[3] = b16(f0.w);
  o[4] = b16(f1.x); o[5] = b16(f1.y); o[6] = b16(f1.z); o[7] = b16(f1.w);
  *(us8*)(dst + i) = o;
}

// ------------- weight transposes (z = which W): Wt[n][k] = bf16(W[k][n]) ----
__global__ __launch_bounds__(256) void transpose_w4_k(
    const float* __restrict__ w0, const float* __restrict__ w1,
    const float* __restrict__ w2, const float* __restrict__ w3,
    unsigned short* __restrict__ t0, unsigned short* __restrict__ t1,
    unsigned short* __restrict__ t2, unsigned short* __restrict__ t3) {
  const float* W = blockIdx.z == 0 ? w0 : blockIdx.z == 1 ? w1
                 : blockIdx.z == 2 ? w2 : w3;
  unsigned short* Wt = blockIdx.z == 0 ? t0 : blockIdx.z == 1 ? t1
                     : blockIdx.z == 2 ? t2 : t3;
  __shared__ float tile[32][33];
  const int ti = blockIdx.x, tj = blockIdx.y;
  const int c = threadIdx.x & 31, r8 = threadIdx.x >> 5;
#pragma unroll
  for (int i = 0; i < 4; i++) {
    int r = r8 * 4 + i;
    tile[r][c] = W[(size_t)(ti * 32 + r) * DM + tj * 32 + c];
  }
  __syncthreads();
#pragma unroll
  for (int i = 0; i < 4; i++) {
    int r = r8 * 4 + i;
    Wt[(size_t)(tj * 32 + r) * DM + ti * 32 + c] = b16(tile[c][r]);
  }
}

// ---- shared GEMM main loop: 128x128 tile, BK=64, dbuf LDS, 2-phase pipeline -
// K-steps swept in per-block ROTATED order (start t0): tile row stride 2048B
// aliases the 8KB HBM channel period (only 4/32 channel groups per k-phase),
// so lockstep blocks queue on the same channels; rotation spreads them.
__device__ __forceinline__ void gemm_mainloop(const char* Ab, const char* Bb,
    char* AsB, char* BsB, int m0, int n0, int tid, int t0,
    f32x4 (&acc)[4][4]) {
  const int lane = tid & 63, w = tid >> 6;
  const int ln = lane & 15, lh = lane >> 4;
  const int wr = w >> 1, wc = w & 1;
  stage128<2048>(Ab, m0, t0 * 128, AsB, tid);
  stage128<2048>(Bb, n0, t0 * 128, BsB, tid);
  __syncthreads();
  for (int i = 0; i < 16; i++) {
    const int cur = (i & 1) << 14, nxt = cur ^ (1 << 14);
    if (i < 15) {
      const int kb = (((t0 + i + 1) & 15)) * 128;
      stage128<2048>(Ab, m0, kb, AsB + nxt, tid);
      stage128<2048>(Bb, n0, kb, BsB + nxt, tid);
    }
#pragma unroll
    for (int ks = 0; ks < 2; ks++) {
      us8 af[4], bf[4];
#pragma unroll
      for (int mi = 0; mi < 4; mi++)
        af[mi] = SWZ_RD(AsB + cur, wr * 64 + mi * 16 + ln, ks * 4 + lh);
#pragma unroll
      for (int c = 0; c < 4; c++)
        bf[c] = SWZ_RD(BsB + cur, wc * 64 + c * 16 + ln, ks * 4 + lh);
#pragma unroll
      for (int mi = 0; mi < 4; mi++)
#pragma unroll
        for (int c = 0; c < 4; c++)
          acc[mi][c] = mfma16(af[mi], bf[c], acc[mi][c]);
    }
    __syncthreads();
  }
}

// -------- fused Q/K/V projection GEMM (blockIdx.z selects which) ------------
__global__ __launch_bounds__(256) void gemm_qkv_k(
    const unsigned short* __restrict__ Aq, const unsigned short* __restrict__ Ak,
    const unsigned short* __restrict__ Av, const unsigned short* __restrict__ Wq,
    const unsigned short* __restrict__ Wk, const unsigned short* __restrict__ Wv,
    const float* __restrict__ bq, const float* __restrict__ bk,
    const float* __restrict__ bv, unsigned short* __restrict__ oq,
    unsigned short* __restrict__ ok, unsigned short* __restrict__ ov,
    float qscale) {
  __shared__ unsigned short As[2 * 128 * 64];  // 32 KB
  __shared__ unsigned short Bs[2 * 128 * 64];  // 32 KB
  const int z = blockIdx.z;
  const unsigned short* A = z == 0 ? Aq : z == 1 ? Ak : Av;
  const unsigned short* Wt = z == 0 ? Wq : z == 1 ? Wk : Wv;
  const float* bias = z == 0 ? bq : z == 1 ? bk : bv;
  unsigned short* out = z == 0 ? oq : z == 1 ? ok : ov;
  const float scale = z == 0 ? qscale : 1.0f;
  const int m0 = blockIdx.x * 128, n0 = blockIdx.y * 128;
  const int tid = threadIdx.x, lane = tid & 63, w = tid >> 6;
  const int ln = lane & 15, lh = lane >> 4;
  const int wr = w >> 1, wc = w & 1;
  const int t0 = (blockIdx.x * 7 + blockIdx.y * 3 + blockIdx.z) & 15;
  f32x4 acc[4][4] = {};
  gemm_mainloop((const char*)A, (const char*)Wt, (char*)As, (char*)Bs,
                m0, n0, tid, t0, acc);
#pragma unroll
  for (int mi = 0; mi < 4; mi++) {
#pragma unroll
    for (int c = 0; c < 4; c++) {
      const int n = n0 + wc * 64 + c * 16 + ln;
      const float bv_ = bias[n];
      const int h = n >> 6, d = n & 63;
      const int mbase = m0 + wr * 64 + mi * 16 + lh * 4;
      if (z < 2) {
#pragma unroll
        for (int r = 0; r < 4; r++) {
          int m = mbase + r, b = m >> 11, s = m & (S_LEN - 1);
          out[((size_t)(b * NH + h) * S_LEN + s) * DEPTH + d] =
              b16((acc[mi][c][r] + bv_) * scale);
        }
      } else {  // V^T [B,H,d,S]
        const int b = mbase >> 11, s = mbase & (S_LEN - 1);
        us4 pk;
#pragma unroll
        for (int r = 0; r < 4; r++) pk[r] = b16(acc[mi][c][r] + bv_);
        *(us4*)&out[((size_t)(b * NH + h) * DEPTH + d) * S_LEN + s] = pk;
      }
    }
  }
}

// ------------- final projection GEMM: f32 out, 64x128 tile -----------------
// R17: grid (64,8) = 512 blocks = 2 blocks/CU (vs 128x128's 256 = 1/CU =
// 1 wave/SIMD, zero TLP to hide LDS/staging latency).
__global__ __launch_bounds__(256) void gemm_out_k(
    const unsigned short* __restrict__ A, const unsigned short* __restrict__ Wt,
    const float* __restrict__ bias, float* __restrict__ out) {
  __shared__ unsigned short As[2 * 64 * 64];   // 16 KB
  __shared__ unsigned short Bs[2 * 128 * 64];  // 32 KB
  char* AsB = (char*)As;
  char* BsB = (char*)Bs;
  const int m0 = blockIdx.x * 64, n0 = blockIdx.y * 128;
  const int tid = threadIdx.x, lane = tid & 63, w = tid >> 6;
  const int ln = lane & 15, lh = lane >> 4;
  const int wr = w >> 1, wc = w & 1;
  const int t0 = (blockIdx.x * 7 + blockIdx.y * 3) & 15;
  const char* Ab = (const char*)A;
  const char* Bb = (const char*)Wt;
  f32x4 acc[2][4] = {};
  stage64a(Ab, m0, t0 * 128, AsB, tid);
  stage128<2048>(Bb, n0, t0 * 128, BsB, tid);
  __syncthreads();
  for (int i = 0; i < 16; i++) {
    const int curA = (i & 1) << 13, curB = (i & 1) << 14;
    if (i < 15) {
      const int kb = ((t0 + i + 1) & 15) * 128;
      stage64a(Ab, m0, kb, AsB + (curA ^ (1 << 13)), tid);
      stage128<2048>(Bb, n0, kb, BsB + (curB ^ (1 << 14)), tid);
    }
#pragma unroll
    for (int ks = 0; ks < 2; ks++) {
      us8 af[2], bf[4];
#pragma unroll
      for (int mi = 0; mi < 2; mi++)
        af[mi] = SWZ_RD(AsB + curA, wr * 32 + mi * 16 + ln, ks * 4 + lh);
#pragma unroll
      for (int c = 0; c < 4; c++)
        bf[c] = SWZ_RD(BsB + curB, wc * 64 + c * 16 + ln, ks * 4 + lh);
#pragma unroll
      for (int mi = 0; mi < 2; mi++)
#pragma unroll
        for (int c = 0; c < 4; c++)
          acc[mi][c] = mfma16(af[mi], bf[c], acc[mi][c]);
    }
    __syncthreads();
  }
#pragma unroll
  for (int mi = 0; mi < 2; mi++) {
#pragma unroll
    for (int c = 0; c < 4; c++) {
      const int n = n0 + wc * 64 + c * 16 + ln;
      const float bv_ = bias[n];
      const int mbase = m0 + wr * 32 + mi * 16 + lh * 4;
#pragma unroll
      for (int r = 0; r < 4; r++)
        out[(size_t)(mbase + r) * DM + n] = acc[mi][c][r] + bv_;
    }
  }
}

// ---------------- attention: swapped QK^T, two-pass softmax -----------------
// Pass 1 (R18): DIRECT-GLOBAL K reads -- K is 256 KB/bh, XCD-pinned L2-resident
// (m169: staging L2-fit data is pure overhead). Zero LDS, zero barriers, zero
// vmcnt(0) drains; 16 waves/CU TLP hides L2 latency.
// Pass 2: staged K (sigma-perm), qt-rotated tile order (R12 de-aliasing),
// normal stores (R13), vmcnt(8)+s_barrier loop end (R16, T4 discipline).
__global__ __launch_bounds__(256) void attn_k(const unsigned short* __restrict__ Qh,
    const unsigned short* __restrict__ Kh, const unsigned short* __restrict__ Vt,
    float* __restrict__ Wout, unsigned short* __restrict__ attnOut) {
  __shared__ unsigned short Ks[2 * 128 * 64];  // 32 KB, dbuf swizzled linear
  char* KsB = (char*)Ks;
  const int flat = blockIdx.x;
  const int xcd = flat & 7, g = flat >> 3;
  const int qt = g & 31;
  const int bh = xcd + 8 * (g >> 5);
  const int tid = threadIdx.x, w = tid >> 6, lane = tid & 63;
  const int ln = lane & 15, lh = lane >> 4;
  const int q0 = qt * 64;
  const unsigned short* Qb = Qh + (size_t)bh * S_LEN * DEPTH;
  const char* KbB = (const char*)(Kh + (size_t)bh * S_LEN * DEPTH);
  const unsigned short* Vb = Vt + (size_t)bh * DEPTH * S_LEN;
  // Q fragment (B-operand): n = q-row = ln, k = depth
  const int qrow = q0 + w * 16 + ln;
  const us8 qf0 = *(const us8*)(Qb + (size_t)qrow * DEPTH + lh * 8);
  const us8 qf1 = *(const us8*)(Qb + (size_t)qrow * DEPTH + 32 + lh * 8);

  // ---- pass 1: l = sum over keys of exp2(score'); direct-global K ----
  float l = 0.f;
#pragma unroll 2
  for (int kb = 0; kb < 64; kb++) {
    const char* Kt = KbB + (size_t)kb * 32 * 128;
    us8 k00 = *(const us8*)(Kt + (size_t)ln * 128 + lh * 16);
    us8 k01 = *(const us8*)(Kt + (size_t)ln * 128 + 64 + lh * 16);
    us8 k10 = *(const us8*)(Kt + (size_t)(ln + 16) * 128 + lh * 16);
    us8 k11 = *(const us8*)(Kt + (size_t)(ln + 16) * 128 + 64 + lh * 16);
    f32x4 d0 = {0.f, 0.f, 0.f, 0.f}, d1 = {0.f, 0.f, 0.f, 0.f};
    d0 = mfma16(k00, qf0, d0);
    d0 = mfma16(k01, qf1, d0);
    d1 = mfma16(k10, qf0, d1);
    d1 = mfma16(k11, qf1, d1);
    l += (ex2(d0[0]) + ex2(d0[1])) + (ex2(d0[2]) + ex2(d0[3])) +
         (ex2(d1[0]) + ex2(d1[1])) + (ex2(d1[2]) + ex2(d1[3]));
  }
  l += __shfl_xor(l, 16);
  l += __shfl_xor(l, 32);
  const float rl = 1.0f / l;

  // ---- pass 2: qt-rotated t-order; weights -> d_out, PV accumulate ----
  f32x4 o[4] = {};
  float* Wr = Wout + (size_t)bh * S_LEN * S_LEN + (size_t)(q0 + w * 16 + ln) * S_LEN;
  const int t0 = qt & 15;
  stage128k(KbB, t0 * 128, KsB, tid);
  __syncthreads();
  for (int i = 0; i < 16; i++) {
    const int t = (t0 + i) & 15;
    const int cur = (i & 1) << 14, nxt = cur ^ (1 << 14);
    if (i < 15) stage128k(KbB, ((t0 + i + 1) & 15) * 128, KsB + nxt, tid);
    __builtin_amdgcn_sched_barrier(0);  // staging loads issue first (oldest in vmcnt FIFO)
    const int sc = t * 128;
#pragma unroll
    for (int kt2 = 0; kt2 < 4; kt2++) {
      const int r0 = kt2 * 32 + ln;
      f32x4 d0 = {0.f, 0.f, 0.f, 0.f}, d1 = {0.f, 0.f, 0.f, 0.f};
      d0 = mfma16(SWZ_RD(KsB + cur, r0, lh), qf0, d0);
      d0 = mfma16(SWZ_RD(KsB + cur, r0, 4 + lh), qf1, d0);
      d1 = mfma16(SWZ_RD(KsB + cur, r0 + 16, lh), qf0, d1);
      d1 = mfma16(SWZ_RD(KsB + cur, r0 + 16, 4 + lh), qf1, d1);
      // lane owns q-row ln, keys sc + kt2*32 + 8*lh + {0..7}
      f32x4 w0, w1;
#pragma unroll
      for (int r = 0; r < 4; r++) {
        w0[r] = ex2(d0[r]) * rl;
        w1[r] = ex2(d1[r]) * rl;
      }
      *(f32x4*)(Wr + sc + kt2 * 32 + 8 * lh) = w0;
      *(f32x4*)(Wr + sc + kt2 * 32 + 8 * lh + 4) = w1;
      // bf16 pack IS the PV A-fragment (row ln, keys 8lh..8lh+7)
      us8 af;
      af[0] = b16(w0[0]); af[1] = b16(w0[1]);
      af[2] = b16(w0[2]); af[3] = b16(w0[3]);
      af[4] = b16(w1[0]); af[5] = b16(w1[1]);
      af[6] = b16(w1[2]); af[7] = b16(w1[3]);
#pragma unroll
      for (int dt = 0; dt < 4; dt++) {
        us8 vf = *(const us8*)(Vb + (size_t)(dt * 16 + ln) * S_LEN + sc +
                               kt2 * 32 + lh * 8);
        o[dt] = mfma16(af, vf, o[dt]);
      }
    }
    // staging (oldest 4 VMEM ops) retired; up to 8 weight stores stay in flight
    asm volatile("s_waitcnt vmcnt(8)" ::: "memory");
    __builtin_amdgcn_s_barrier();
  }

  const int b = bh >> 4, h = bh & 15;
#pragma unroll
  for (int dt = 0; dt < 4; dt++) {
#pragma unroll
    for (int r = 0; r < 4; r++) {
      size_t row = (size_t)b * S_LEN + q0 + w * 16 + lh * 4 + r;
      attnOut[row * DM + h * DEPTH + dt * 16 + ln] = b16(o[dt][r]);
    }
  }
}

extern "C" void kernel_launch(void* const* d_in, const int* in_sizes, int n_in,
                              void* d_out, int out_size, void* d_ws, size_t ws_size,
                              hipStream_t stream) {
  const float* queries = (const float*)d_in[0];
  const float* keys    = (const float*)d_in[1];
  const float* values  = (const float*)d_in[2];
  const float* wq = (const float*)d_in[3];
  const float* bq = (const float*)d_in[4];
  const float* wk = (const float*)d_in[5];
  const float* bk = (const float*)d_in[6];
  const float* wv = (const float*)d_in[7];
  const float* bv = (const float*)d_in[8];
  const float* wo = (const float*)d_in[9];
  const float* bo = (const float*)d_in[10];

  float* out = (float*)d_out;
  float* wts = out + (size_t)BATCH * S_LEN * DM;  // weights output after `out`

  char* ws = (char*)d_ws;
  const size_t WSZ = (size_t)DM * DM * sizeof(unsigned short);            // 2 MB
  const size_t TSZ = (size_t)BATCH * S_LEN * DM * sizeof(unsigned short); // 8 MB
  unsigned short* Wqt = (unsigned short*)(ws + 0 * WSZ);
  unsigned short* Wkt = (unsigned short*)(ws + 1 * WSZ);
  unsigned short* Wvt = (unsigned short*)(ws + 2 * WSZ);
  unsigned short* Wot = (unsigned short*)(ws + 3 * WSZ);
  unsigned short* Qbf = (unsigned short*)(ws + 4 * WSZ + 0 * TSZ);
  unsigned short* Kbf = (unsigned short*)(ws + 4 * WSZ + 1 * TSZ);
  unsigned short* Vbf = (unsigned short*)(ws + 4 * WSZ + 2 * TSZ);
  unsigned short* Qhd = (unsigned short*)(ws + 4 * WSZ + 3 * TSZ);
  unsigned short* Khd = (unsigned short*)(ws + 4 * WSZ + 4 * TSZ);
  unsigned short* Vtd = (unsigned short*)(ws + 4 * WSZ + 5 * TSZ);
  unsigned short* attn = Qbf;  // Qbf dead after Q-projection; reuse for attn out

  cvt3_k<<<dim3(2048, 3), 256, 0, stream>>>(queries, keys, values, Qbf, Kbf, Vbf);
  transpose_w4_k<<<dim3(32, 32, 4), 256, 0, stream>>>(wq, wk, wv, wo,
                                                      Wqt, Wkt, Wvt, Wot);
  gemm_qkv_k<<<dim3(32, 8, 3), 256, 0, stream>>>(Qbf, Kbf, Vbf, Wqt, Wkt, Wvt,
                                                 bq, bk, bv, Qhd, Khd, Vtd,
                                                 0.125f * LOG2E);
  attn_k<<<1024, 256, 0, stream>>>(Qhd, Khd, Vtd, wts, attn);
  gemm_out_k<<<dim3(64, 8), 256, 0, stream>>>(attn, Wot, bo, out);
}

// Round 19
// 288.856 us; speedup vs baseline: 1.2913x; 1.2913x over previous
//
#include <hip/hip_runtime.h>
#include <hip/hip_bf16.h>

#define DM 1024
#define S_LEN 2048
#define NH 16
#define DEPTH 64
#define BATCH 2
#define LOG2E 1.4426950408889634f

typedef float f32x4 __attribute__((ext_vector_type(4)));
typedef __bf16 bf16x8 __attribute__((ext_vector_type(8)));
typedef unsigned short us8 __attribute__((ext_vector_type(8)));
typedef unsigned short us4 __attribute__((ext_vector_type(4)));

__device__ __forceinline__ unsigned short b16(float f) {
  return __builtin_bit_cast(unsigned short, (__bf16)f);
}
__device__ __forceinline__ float ex2(float x) {
#if __has_builtin(__builtin_amdgcn_exp2f)
  return __builtin_amdgcn_exp2f(x);
#else
  return exp2f(x);
#endif
}
__device__ __forceinline__ f32x4 mfma16(us8 a, us8 b, f32x4 c) {
  return __builtin_amdgcn_mfma_f32_16x16x32_bf16(
      __builtin_bit_cast(bf16x8, a), __builtin_bit_cast(bf16x8, b), c, 0, 0, 0);
}
// async global->LDS, 16B per lane; LDS dest = wave-uniform base (+lane*16 by HW)
__device__ __forceinline__ void gll16(const void* g, void* l) {
  __builtin_amdgcn_global_load_lds(
      (const __attribute__((address_space(1))) void*)g,
      (__attribute__((address_space(3))) void*)l, 16, 0, 0);
}
// swizzled LDS read: 16B chunk c of row r lives at slot c^(r&7); rows are 128B
#define SWZ_RD(baseB, r, c) \
  (*(const us8*)((baseB) + (size_t)(r) * 128 + ((((c) ^ ((r) & 7))) << 4)))

// stage a 128-row x 128B tile (global rows r0.., row stride RSB bytes) into LDS
// dst, inverse-swizzled source so SWZ_RD sees chunk^(row&7). 4 gll16/thread.
template <int RSB>
__device__ __forceinline__ void stage128(const char* Gb, int r0, int kb,
                                         char* dst, int tid) {
#pragma unroll
  for (int i = 0; i < 4; i++) {
    int t16 = i * 256 + tid;
    int row = t16 >> 3;
    int g = (t16 & 7) ^ (row & 7);
    gll16(Gb + (size_t)(r0 + row) * RSB + kb + (g << 4),
          dst + i * 4096 + (tid & ~63) * 16);
  }
}

// 64-row x 128B tile (row stride 2048B): 2 gll16/thread = 8 KB.
__device__ __forceinline__ void stage64a(const char* Gb, int r0, int kb,
                                         char* dst, int tid) {
#pragma unroll
  for (int i = 0; i < 2; i++) {
    int t16 = i * 256 + tid;
    int row = t16 >> 3;
    int g = (t16 & 7) ^ (row & 7);
    gll16(Gb + (size_t)(r0 + row) * 2048 + kb + (g << 4),
          dst + i * 4096 + (tid & ~63) * 16);
  }
}

// K staging (128 rows, 512-thread blocks) with per-32-row-block sigma
// permutation: LDS row i holds key sigma(i) so QK^T's C/D lane mapping directly
// yields PV A-fragment key order (keys 8*lh..8*lh+7 per lane). 2 gll16/thread.
__device__ __forceinline__ void stage128k_512(const char* Gb, int r0, char* dst,
                                              int tid) {
#pragma unroll
  for (int i = 0; i < 2; i++) {
    int t16 = i * 512 + tid;
    int row = t16 >> 3;
    int g = (t16 & 7) ^ (row & 7);
    int i5 = row & 31, jj = i5 & 15, hi = i5 >> 4;
    int prow = (row & 96) | ((jj >> 2) << 3) | (hi << 2) | (jj & 3);
    gll16(Gb + (size_t)(r0 + prow) * 128 + (g << 4),
          dst + i * 8192 + (tid & ~63) * 16);
  }
}

// ---------------- f32 -> bf16 convert for q/k/v activations ----------------
__global__ __launch_bounds__(256) void cvt3_k(const float* __restrict__ q,
    const float* __restrict__ k, const float* __restrict__ v,
    unsigned short* __restrict__ oq, unsigned short* __restrict__ ok,
    unsigned short* __restrict__ ov) {
  const float* src = blockIdx.y == 0 ? q : blockIdx.y == 1 ? k : v;
  unsigned short* dst = blockIdx.y == 0 ? oq : blockIdx.y == 1 ? ok : ov;
  size_t i = ((size_t)blockIdx.x * 256 + threadIdx.x) * 8;
  float4 f0 = *(const float4*)(src + i);
  float4 f1 = *(const float4*)(src + i + 4);
  us8 o;
  o[0] = b16(f0.x); o[1] = b16(f0.y); o[2] = b16(f0.z); o[3] = b16(f0.w);
  o[4] = b16(f1.x); o[5] = b16(f1.y); o[6] = b16(f1.z); o[7] = b16(f1.w);
  *(us8*)(dst + i) = o;
}

// ------------- weight transposes (z = which W): Wt[n][k] = bf16(W[k][n]) ----
__global__ __launch_bounds__(256) void transpose_w4_k(
    const float* __restrict__ w0, const float* __restrict__ w1,
    const float* __restrict__ w2, const float* __restrict__ w3,
    unsigned short* __restrict__ t0, unsigned short* __restrict__ t1,
    unsigned short* __restrict__ t2, unsigned short* __restrict__ t3) {
  const float* W = blockIdx.z == 0 ? w0 : blockIdx.z == 1 ? w1
                 : blockIdx.z == 2 ? w2 : w3;
  unsigned short* Wt = blockIdx.z == 0 ? t0 : blockIdx.z == 1 ? t1
                     : blockIdx.z == 2 ? t2 : t3;
  __shared__ float tile[32][33];
  const int ti = blockIdx.x, tj = blockIdx.y;
  const int c = threadIdx.x & 31, r8 = threadIdx.x >> 5;
#pragma unroll
  for (int i = 0; i < 4; i++) {
    int r = r8 * 4 + i;
    tile[r][c] = W[(size_t)(ti * 32 + r) * DM + tj * 32 + c];
  }
  __syncthreads();
#pragma unroll
  for (int i = 0; i < 4; i++) {
    int r = r8 * 4 + i;
    Wt[(size_t)(tj * 32 + r) * DM + ti * 32 + c] = b16(tile[c][r]);
  }
}

// ---- shared GEMM main loop: 128x128 tile, BK=64, dbuf LDS, 2-phase pipeline -
// K-steps swept in per-block ROTATED order (start t0): tile row stride 2048B
// aliases the 8KB HBM channel period (only 4/32 channel groups per k-phase),
// so lockstep blocks queue on the same channels; rotation spreads them.
__device__ __forceinline__ void gemm_mainloop(const char* Ab, const char* Bb,
    char* AsB, char* BsB, int m0, int n0, int tid, int t0,
    f32x4 (&acc)[4][4]) {
  const int lane = tid & 63, w = tid >> 6;
  const int ln = lane & 15, lh = lane >> 4;
  const int wr = w >> 1, wc = w & 1;
  stage128<2048>(Ab, m0, t0 * 128, AsB, tid);
  stage128<2048>(Bb, n0, t0 * 128, BsB, tid);
  __syncthreads();
  for (int i = 0; i < 16; i++) {
    const int cur = (i & 1) << 14, nxt = cur ^ (1 << 14);
    if (i < 15) {
      const int kb = (((t0 + i + 1) & 15)) * 128;
      stage128<2048>(Ab, m0, kb, AsB + nxt, tid);
      stage128<2048>(Bb, n0, kb, BsB + nxt, tid);
    }
#pragma unroll
    for (int ks = 0; ks < 2; ks++) {
      us8 af[4], bf[4];
#pragma unroll
      for (int mi = 0; mi < 4; mi++)
        af[mi] = SWZ_RD(AsB + cur, wr * 64 + mi * 16 + ln, ks * 4 + lh);
#pragma unroll
      for (int c = 0; c < 4; c++)
        bf[c] = SWZ_RD(BsB + cur, wc * 64 + c * 16 + ln, ks * 4 + lh);
#pragma unroll
      for (int mi = 0; mi < 4; mi++)
#pragma unroll
        for (int c = 0; c < 4; c++)
          acc[mi][c] = mfma16(af[mi], bf[c], acc[mi][c]);
    }
    __syncthreads();
  }
}

// -------- fused Q/K/V projection GEMM (blockIdx.z selects which) ------------
__global__ __launch_bounds__(256) void gemm_qkv_k(
    const unsigned short* __restrict__ Aq, const unsigned short* __restrict__ Ak,
    const unsigned short* __restrict__ Av, const unsigned short* __restrict__ Wq,
    const unsigned short* __restrict__ Wk, const unsigned short* __restrict__ Wv,
    const float* __restrict__ bq, const float* __restrict__ bk,
    const float* __restrict__ bv, unsigned short* __restrict__ oq,
    unsigned short* __restrict__ ok, unsigned short* __restrict__ ov,
    float qscale) {
  __shared__ unsigned short As[2 * 128 * 64];  // 32 KB
  __shared__ unsigned short Bs[2 * 128 * 64];  // 32 KB
  const int z = blockIdx.z;
  const unsigned short* A = z == 0 ? Aq : z == 1 ? Ak : Av;
  const unsigned short* Wt = z == 0 ? Wq : z == 1 ? Wk : Wv;
  const float* bias = z == 0 ? bq : z == 1 ? bk : bv;
  unsigned short* out = z == 0 ? oq : z == 1 ? ok : ov;
  const float scale = z == 0 ? qscale : 1.0f;
  const int m0 = blockIdx.x * 128, n0 = blockIdx.y * 128;
  const int tid = threadIdx.x, lane = tid & 63, w = tid >> 6;
  const int ln = lane & 15, lh = lane >> 4;
  const int wr = w >> 1, wc = w & 1;
  const int t0 = (blockIdx.x * 7 + blockIdx.y * 3 + blockIdx.z) & 15;
  f32x4 acc[4][4] = {};
  gemm_mainloop((const char*)A, (const char*)Wt, (char*)As, (char*)Bs,
                m0, n0, tid, t0, acc);
#pragma unroll
  for (int mi = 0; mi < 4; mi++) {
#pragma unroll
    for (int c = 0; c < 4; c++) {
      const int n = n0 + wc * 64 + c * 16 + ln;
      const float bv_ = bias[n];
      const int h = n >> 6, d = n & 63;
      const int mbase = m0 + wr * 64 + mi * 16 + lh * 4;
      if (z < 2) {
#pragma unroll
        for (int r = 0; r < 4; r++) {
          int m = mbase + r, b = m >> 11, s = m & (S_LEN - 1);
          out[((size_t)(b * NH + h) * S_LEN + s) * DEPTH + d] =
              b16((acc[mi][c][r] + bv_) * scale);
        }
      } else {  // V^T [B,H,d,S]
        const int b = mbase >> 11, s = mbase & (S_LEN - 1);
        us4 pk;
#pragma unroll
        for (int r = 0; r < 4; r++) pk[r] = b16(acc[mi][c][r] + bv_);
        *(us4*)&out[((size_t)(b * NH + h) * DEPTH + d) * S_LEN + s] = pk;
      }
    }
  }
}

// ------------- final projection GEMM: f32 out, 64x128 tile -----------------
// R17: grid (64,8) = 512 blocks = 2 blocks/CU (vs 128x128's 256 = 1/CU =
// 1 wave/SIMD, zero TLP to hide LDS/staging latency).
__global__ __launch_bounds__(256) void gemm_out_k(
    const unsigned short* __restrict__ A, const unsigned short* __restrict__ Wt,
    const float* __restrict__ bias, float* __restrict__ out) {
  __shared__ unsigned short As[2 * 64 * 64];   // 16 KB
  __shared__ unsigned short Bs[2 * 128 * 64];  // 32 KB
  char* AsB = (char*)As;
  char* BsB = (char*)Bs;
  const int m0 = blockIdx.x * 64, n0 = blockIdx.y * 128;
  const int tid = threadIdx.x, lane = tid & 63, w = tid >> 6;
  const int ln = lane & 15, lh = lane >> 4;
  const int wr = w >> 1, wc = w & 1;
  const int t0 = (blockIdx.x * 7 + blockIdx.y * 3) & 15;
  const char* Ab = (const char*)A;
  const char* Bb = (const char*)Wt;
  f32x4 acc[2][4] = {};
  stage64a(Ab, m0, t0 * 128, AsB, tid);
  stage128<2048>(Bb, n0, t0 * 128, BsB, tid);
  __syncthreads();
  for (int i = 0; i < 16; i++) {
    const int curA = (i & 1) << 13, curB = (i & 1) << 14;
    if (i < 15) {
      const int kb = ((t0 + i + 1) & 15) * 128;
      stage64a(Ab, m0, kb, AsB + (curA ^ (1 << 13)), tid);
      stage128<2048>(Bb, n0, kb, BsB + (curB ^ (1 << 14)), tid);
    }
#pragma unroll
    for (int ks = 0; ks < 2; ks++) {
      us8 af[2], bf[4];
#pragma unroll
      for (int mi = 0; mi < 2; mi++)
        af[mi] = SWZ_RD(AsB + curA, wr * 32 + mi * 16 + ln, ks * 4 + lh);
#pragma unroll
      for (int c = 0; c < 4; c++)
        bf[c] = SWZ_RD(BsB + curB, wc * 64 + c * 16 + ln, ks * 4 + lh);
#pragma unroll
      for (int mi = 0; mi < 2; mi++)
#pragma unroll
        for (int c = 0; c < 4; c++)
          acc[mi][c] = mfma16(af[mi], bf[c], acc[mi][c]);
    }
    __syncthreads();
  }
#pragma unroll
  for (int mi = 0; mi < 2; mi++) {
#pragma unroll
    for (int c = 0; c < 4; c++) {
      const int n = n0 + wc * 64 + c * 16 + ln;
      const float bv_ = bias[n];
      const int mbase = m0 + wr * 32 + mi * 16 + lh * 4;
#pragma unroll
      for (int r = 0; r < 4; r++)
        out[(size_t)(mbase + r) * DM + n] = acc[mi][c][r] + bv_;
    }
  }
}

// ---------------- attention: swapped QK^T, two-pass softmax -----------------
// R19: 512-thread blocks, QBLK=128 (8 waves x 16 q-rows), grid 512.
// Halves K-staging traffic in both passes (16 blocks/bh vs 32), raises
// occupancy 20 -> 32 waves/CU (32 KB LDS amortized over 2x threads).
// Pass 1: staged K (R18's direct-global regressed +93us -- staging wins even
// for L2-resident data). Pass 2: qt-rotated tile order (R12; qt spans 0..15
// per XCD -> 16 store phases), normal stores (R13), vmcnt(8)+s_barrier (R16).
__global__ __launch_bounds__(512) void attn_k(const unsigned short* __restrict__ Qh,
    const unsigned short* __restrict__ Kh, const unsigned short* __restrict__ Vt,
    float* __restrict__ Wout, unsigned short* __restrict__ attnOut) {
  __shared__ unsigned short Ks[2 * 128 * 64];  // 32 KB, dbuf swizzled linear
  char* KsB = (char*)Ks;
  const int flat = blockIdx.x;
  const int xcd = flat & 7, g = flat >> 3;
  const int qt = g & 15;
  const int bh = xcd + 8 * (g >> 4);
  const int tid = threadIdx.x, w = tid >> 6, lane = tid & 63;
  const int ln = lane & 15, lh = lane >> 4;
  const int q0 = qt * 128;
  const unsigned short* Qb = Qh + (size_t)bh * S_LEN * DEPTH;
  const char* KbB = (const char*)(Kh + (size_t)bh * S_LEN * DEPTH);
  const unsigned short* Vb = Vt + (size_t)bh * DEPTH * S_LEN;
  // Q fragment (B-operand): n = q-row = ln, k = depth
  const int qrow = q0 + w * 16 + ln;
  const us8 qf0 = *(const us8*)(Qb + (size_t)qrow * DEPTH + lh * 8);
  const us8 qf1 = *(const us8*)(Qb + (size_t)qrow * DEPTH + 32 + lh * 8);

  // ---- pass 1: l = sum over keys of exp2(score') for q-row qrow ----
  float l = 0.f;
  stage128k_512(KbB, 0, KsB, tid);
  __syncthreads();
  for (int t = 0; t < 16; t++) {
    const int cur = (t & 1) << 14, nxt = cur ^ (1 << 14);
    if (t < 15) stage128k_512(KbB, (t + 1) * 128, KsB + nxt, tid);
#pragma unroll
    for (int kt2 = 0; kt2 < 4; kt2++) {
      const int r0 = kt2 * 32 + ln;
      f32x4 d0 = {0.f, 0.f, 0.f, 0.f}, d1 = {0.f, 0.f, 0.f, 0.f};
      d0 = mfma16(SWZ_RD(KsB + cur, r0, lh), qf0, d0);
      d0 = mfma16(SWZ_RD(KsB + cur, r0, 4 + lh), qf1, d0);
      d1 = mfma16(SWZ_RD(KsB + cur, r0 + 16, lh), qf0, d1);
      d1 = mfma16(SWZ_RD(KsB + cur, r0 + 16, 4 + lh), qf1, d1);
      l += (ex2(d0[0]) + ex2(d0[1])) + (ex2(d0[2]) + ex2(d0[3])) +
           (ex2(d1[0]) + ex2(d1[1])) + (ex2(d1[2]) + ex2(d1[3]));
    }
    __syncthreads();
  }
  l += __shfl_xor(l, 16);
  l += __shfl_xor(l, 32);
  const float rl = 1.0f / l;

  // ---- pass 2: qt-rotated t-order; weights -> d_out, PV accumulate ----
  f32x4 o[4] = {};
  float* Wr = Wout + (size_t)bh * S_LEN * S_LEN + (size_t)qrow * S_LEN;
  const int t0 = qt & 15;
  stage128k_512(KbB, t0 * 128, KsB, tid);
  __syncthreads();
  for (int i = 0; i < 16; i++) {
    const int t = (t0 + i) & 15;
    const int cur = (i & 1) << 14, nxt = cur ^ (1 << 14);
    if (i < 15) stage128k_512(KbB, ((t0 + i + 1) & 15) * 128, KsB + nxt, tid);
    __builtin_amdgcn_sched_barrier(0);  // staging loads issue first (oldest in vmcnt FIFO)
    const int sc = t * 128;
#pragma unroll
    for (int kt2 = 0; kt2 < 4; kt2++) {
      const int r0 = kt2 * 32 + ln;
      f32x4 d0 = {0.f, 0.f, 0.f, 0.f}, d1 = {0.f, 0.f, 0.f, 0.f};
      d0 = mfma16(SWZ_RD(KsB + cur, r0, lh), qf0, d0);
      d0 = mfma16(SWZ_RD(KsB + cur, r0, 4 + lh), qf1, d0);
      d1 = mfma16(SWZ_RD(KsB + cur, r0 + 16, lh), qf0, d1);
      d1 = mfma16(SWZ_RD(KsB + cur, r0 + 16, 4 + lh), qf1, d1);
      // lane owns q-row qrow, keys sc + kt2*32 + 8*lh + {0..7}
      f32x4 w0, w1;
#pragma unroll
      for (int r = 0; r < 4; r++) {
        w0[r] = ex2(d0[r]) * rl;
        w1[r] = ex2(d1[r]) * rl;
      }
      *(f32x4*)(Wr + sc + kt2 * 32 + 8 * lh) = w0;
      *(f32x4*)(Wr + sc + kt2 * 32 + 8 * lh + 4) = w1;
      // bf16 pack IS the PV A-fragment (row qrow, keys 8lh..8lh+7)
      us8 af;
      af[0] = b16(w0[0]); af[1] = b16(w0[1]);
      af[2] = b16(w0[2]); af[3] = b16(w0[3]);
      af[4] = b16(w1[0]); af[5] = b16(w1[1]);
      af[6] = b16(w1[2]); af[7] = b16(w1[3]);
#pragma unroll
      for (int dt = 0; dt < 4; dt++) {
        us8 vf = *(const us8*)(Vb + (size_t)(dt * 16 + ln) * S_LEN + sc +
                               kt2 * 32 + lh * 8);
        o[dt] = mfma16(af, vf, o[dt]);
      }
    }
    // staging (oldest 2 VMEM ops) retired; up to 8 weight stores stay in flight
    asm volatile("s_waitcnt vmcnt(8)" ::: "memory");
    __builtin_amdgcn_s_barrier();
  }

  const int b = bh >> 4, h = bh & 15;
#pragma unroll
  for (int dt = 0; dt < 4; dt++) {
#pragma unroll
    for (int r = 0; r < 4; r++) {
      size_t row = (size_t)b * S_LEN + q0 + w * 16 + lh * 4 + r;
      attnOut[row * DM + h * DEPTH + dt * 16 + ln] = b16(o[dt][r]);
    }
  }
}

extern "C" void kernel_launch(void* const* d_in, const int* in_sizes, int n_in,
                              void* d_out, int out_size, void* d_ws, size_t ws_size,
                              hipStream_t stream) {
  const float* queries = (const float*)d_in[0];
  const float* keys    = (const float*)d_in[1];
  const float* values  = (const float*)d_in[2];
  const float* wq = (const float*)d_in[3];
  const float* bq = (const float*)d_in[4];
  const float* wk = (const float*)d_in[5];
  const float* bk = (const float*)d_in[6];
  const float* wv = (const float*)d_in[7];
  const float* bv = (const float*)d_in[8];
  const float* wo = (const float*)d_in[9];
  const float* bo = (const float*)d_in[10];

  float* out = (float*)d_out;
  float* wts = out + (size_t)BATCH * S_LEN * DM;  // weights output after `out`

  char* ws = (char*)d_ws;
  const size_t WSZ = (size_t)DM * DM * sizeof(unsigned short);            // 2 MB
  const size_t TSZ = (size_t)BATCH * S_LEN * DM * sizeof(unsigned short); // 8 MB
  unsigned short* Wqt = (unsigned short*)(ws + 0 * WSZ);
  unsigned short* Wkt = (unsigned short*)(ws + 1 * WSZ);
  unsigned short* Wvt = (unsigned short*)(ws + 2 * WSZ);
  unsigned short* Wot = (unsigned short*)(ws + 3 * WSZ);
  unsigned short* Qbf = (unsigned short*)(ws + 4 * WSZ + 0 * TSZ);
  unsigned short* Kbf = (unsigned short*)(ws + 4 * WSZ + 1 * TSZ);
  unsigned short* Vbf = (unsigned short*)(ws + 4 * WSZ + 2 * TSZ);
  unsigned short* Qhd = (unsigned short*)(ws + 4 * WSZ + 3 * TSZ);
  unsigned short* Khd = (unsigned short*)(ws + 4 * WSZ + 4 * TSZ);
  unsigned short* Vtd = (unsigned short*)(ws + 4 * WSZ + 5 * TSZ);
  unsigned short* attn = Qbf;  // Qbf dead after Q-projection; reuse for attn out

  cvt3_k<<<dim3(2048, 3), 256, 0, stream>>>(queries, keys, values, Qbf, Kbf, Vbf);
  transpose_w4_k<<<dim3(32, 32, 4), 256, 0, stream>>>(wq, wk, wv, wo,
                                                      Wqt, Wkt, Wvt, Wot);
  gemm_qkv_k<<<dim3(32, 8, 3), 256, 0, stream>>>(Qbf, Kbf, Vbf, Wqt, Wkt, Wvt,
                                                 bq, bk, bv, Qhd, Khd, Vtd,
                                                 0.125f * LOG2E);
  attn_k<<<512, 512, 0, stream>>>(Qhd, Khd, Vtd, wts, attn);
  gemm_out_k<<<dim3(64, 8), 256, 0, stream>>>(attn, Wot, bo, out);
}

// Round 20
// 282.991 us; speedup vs baseline: 1.3181x; 1.0207x over previous
//
#include <hip/hip_runtime.h>
#include <hip/hip_bf16.h>

#define DM 1024
#define S_LEN 2048
#define NH 16
#define DEPTH 64
#define BATCH 2
#define LOG2E 1.4426950408889634f

typedef float f32x4 __attribute__((ext_vector_type(4)));
typedef __bf16 bf16x8 __attribute__((ext_vector_type(8)));
typedef unsigned short us8 __attribute__((ext_vector_type(8)));
typedef unsigned short us4 __attribute__((ext_vector_type(4)));

__device__ __forceinline__ unsigned short b16(float f) {
  return __builtin_bit_cast(unsigned short, (__bf16)f);
}
__device__ __forceinline__ float ex2(float x) {
#if __has_builtin(__builtin_amdgcn_exp2f)
  return __builtin_amdgcn_exp2f(x);
#else
  return exp2f(x);
#endif
}
__device__ __forceinline__ f32x4 mfma16(us8 a, us8 b, f32x4 c) {
  return __builtin_amdgcn_mfma_f32_16x16x32_bf16(
      __builtin_bit_cast(bf16x8, a), __builtin_bit_cast(bf16x8, b), c, 0, 0, 0);
}
// async global->LDS, 16B per lane; LDS dest = wave-uniform base (+lane*16 by HW)
__device__ __forceinline__ void gll16(const void* g, void* l) {
  __builtin_amdgcn_global_load_lds(
      (const __attribute__((address_space(1))) void*)g,
      (__attribute__((address_space(3))) void*)l, 16, 0, 0);
}
// swizzled LDS read: 16B chunk c of row r lives at slot c^(r&7); rows are 128B
#define SWZ_RD(baseB, r, c) \
  (*(const us8*)((baseB) + (size_t)(r) * 128 + ((((c) ^ ((r) & 7))) << 4)))

// stage a 128-row x 128B tile (global rows r0.., row stride RSB bytes) into LDS
// dst, inverse-swizzled source so SWZ_RD sees chunk^(row&7). 4 gll16/thread.
template <int RSB>
__device__ __forceinline__ void stage128(const char* Gb, int r0, int kb,
                                         char* dst, int tid) {
#pragma unroll
  for (int i = 0; i < 4; i++) {
    int t16 = i * 256 + tid;
    int row = t16 >> 3;
    int g = (t16 & 7) ^ (row & 7);
    gll16(Gb + (size_t)(r0 + row) * RSB + kb + (g << 4),
          dst + i * 4096 + (tid & ~63) * 16);
  }
}

// 64-row x 128B tile (row stride 2048B): 2 gll16/thread = 8 KB.
__device__ __forceinline__ void stage64a(const char* Gb, int r0, int kb,
                                         char* dst, int tid) {
#pragma unroll
  for (int i = 0; i < 2; i++) {
    int t16 = i * 256 + tid;
    int row = t16 >> 3;
    int g = (t16 & 7) ^ (row & 7);
    gll16(Gb + (size_t)(r0 + row) * 2048 + kb + (g << 4),
          dst + i * 4096 + (tid & ~63) * 16);
  }
}

// K staging (128 rows) with per-32-row-block sigma permutation: LDS row i holds
// key sigma(i) so QK^T's C/D lane mapping directly yields PV A-fragment key
// order (keys 8*lh..8*lh+7 per lane).
__device__ __forceinline__ void stage128k(const char* Gb, int r0, char* dst,
                                          int tid) {
#pragma unroll
  for (int i = 0; i < 4; i++) {
    int t16 = i * 256 + tid;
    int row = t16 >> 3;
    int g = (t16 & 7) ^ (row & 7);
    int i5 = row & 31, jj = i5 & 15, hi = i5 >> 4;
    int prow = (row & 96) | ((jj >> 2) << 3) | (hi << 2) | (jj & 3);
    gll16(Gb + (size_t)(r0 + prow) * 128 + (g << 4),
          dst + i * 4096 + (tid & ~63) * 16);
  }
}

// ---------------- f32 -> bf16 convert for q/k/v activations ----------------
__global__ __launch_bounds__(256) void cvt3_k(const float* __restrict__ q,
    const float* __restrict__ k, const float* __restrict__ v,
    unsigned short* __restrict__ oq, unsigned short* __restrict__ ok,
    unsigned short* __restrict__ ov) {
  const float* src = blockIdx.y == 0 ? q : blockIdx.y == 1 ? k : v;
  unsigned short* dst = blockIdx.y == 0 ? oq : blockIdx.y == 1 ? ok : ov;
  size_t i = ((size_t)blockIdx.x * 256 + threadIdx.x) * 8;
  float4 f0 = *(const float4*)(src + i);
  float4 f1 = *(const float4*)(src + i + 4);
  us8 o;
  o[0] = b16(f0.x); o[1] = b16(f0.y); o[2] = b16(f0.z); o[3] = b16(f0.w);
  o[4] = b16(f1.x); o[5] = b16(f1.y); o[6] = b16(f1.z); o[7] = b16(f1.w);
  *(us8*)(dst + i) = o;
}

// ------------- weight transposes (z = which W): Wt[n][k] = bf16(W[k][n]) ----
__global__ __launch_bounds__(256) void transpose_w4_k(
    const float* __restrict__ w0, const float* __restrict__ w1,
    const float* __restrict__ w2, const float* __restrict__ w3,
    unsigned short* __restrict__ t0, unsigned short* __restrict__ t1,
    unsigned short* __restrict__ t2, unsigned short* __restrict__ t3) {
  const float* W = blockIdx.z == 0 ? w0 : blockIdx.z == 1 ? w1
                 : blockIdx.z == 2 ? w2 : w3;
  unsigned short* Wt = blockIdx.z == 0 ? t0 : blockIdx.z == 1 ? t1
                     : blockIdx.z == 2 ? t2 : t3;
  __shared__ float tile[32][33];
  const int ti = blockIdx.x, tj = blockIdx.y;
  const int c = threadIdx.x & 31, r8 = threadIdx.x >> 5;
#pragma unroll
  for (int i = 0; i < 4; i++) {
    int r = r8 * 4 + i;
    tile[r][c] = W[(size_t)(ti * 32 + r) * DM + tj * 32 + c];
  }
  __syncthreads();
#pragma unroll
  for (int i = 0; i < 4; i++) {
    int r = r8 * 4 + i;
    Wt[(size_t)(tj * 32 + r) * DM + ti * 32 + c] = b16(tile[c][r]);
  }
}

// ---- shared GEMM main loop: 128x128 tile, BK=64, dbuf LDS, 2-phase pipeline -
// K-steps swept in per-block ROTATED order (start t0): tile row stride 2048B
// aliases the 8KB HBM channel period (only 4/32 channel groups per k-phase),
// so lockstep blocks queue on the same channels; rotation spreads them.
__device__ __forceinline__ void gemm_mainloop(const char* Ab, const char* Bb,
    char* AsB, char* BsB, int m0, int n0, int tid, int t0,
    f32x4 (&acc)[4][4]) {
  const int lane = tid & 63, w = tid >> 6;
  const int ln = lane & 15, lh = lane >> 4;
  const int wr = w >> 1, wc = w & 1;
  stage128<2048>(Ab, m0, t0 * 128, AsB, tid);
  stage128<2048>(Bb, n0, t0 * 128, BsB, tid);
  __syncthreads();
  for (int i = 0; i < 16; i++) {
    const int cur = (i & 1) << 14, nxt = cur ^ (1 << 14);
    if (i < 15) {
      const int kb = (((t0 + i + 1) & 15)) * 128;
      stage128<2048>(Ab, m0, kb, AsB + nxt, tid);
      stage128<2048>(Bb, n0, kb, BsB + nxt, tid);
    }
#pragma unroll
    for (int ks = 0; ks < 2; ks++) {
      us8 af[4], bf[4];
#pragma unroll
      for (int mi = 0; mi < 4; mi++)
        af[mi] = SWZ_RD(AsB + cur, wr * 64 + mi * 16 + ln, ks * 4 + lh);
#pragma unroll
      for (int c = 0; c < 4; c++)
        bf[c] = SWZ_RD(BsB + cur, wc * 64 + c * 16 + ln, ks * 4 + lh);
#pragma unroll
      for (int mi = 0; mi < 4; mi++)
#pragma unroll
        for (int c = 0; c < 4; c++)
          acc[mi][c] = mfma16(af[mi], bf[c], acc[mi][c]);
    }
    __syncthreads();
  }
}

// -------- fused Q/K/V projection GEMM (blockIdx.z selects which) ------------
__global__ __launch_bounds__(256) void gemm_qkv_k(
    const unsigned short* __restrict__ Aq, const unsigned short* __restrict__ Ak,
    const unsigned short* __restrict__ Av, const unsigned short* __restrict__ Wq,
    const unsigned short* __restrict__ Wk, const unsigned short* __restrict__ Wv,
    const float* __restrict__ bq, const float* __restrict__ bk,
    const float* __restrict__ bv, unsigned short* __restrict__ oq,
    unsigned short* __restrict__ ok, unsigned short* __restrict__ ov,
    float qscale) {
  __shared__ unsigned short As[2 * 128 * 64];  // 32 KB
  __shared__ unsigned short Bs[2 * 128 * 64];  // 32 KB
  const int z = blockIdx.z;
  const unsigned short* A = z == 0 ? Aq : z == 1 ? Ak : Av;
  const unsigned short* Wt = z == 0 ? Wq : z == 1 ? Wk : Wv;
  const float* bias = z == 0 ? bq : z == 1 ? bk : bv;
  unsigned short* out = z == 0 ? oq : z == 1 ? ok : ov;
  const float scale = z == 0 ? qscale : 1.0f;
  const int m0 = blockIdx.x * 128, n0 = blockIdx.y * 128;
  const int tid = threadIdx.x, lane = tid & 63, w = tid >> 6;
  const int ln = lane & 15, lh = lane >> 4;
  const int wr = w >> 1, wc = w & 1;
  const int t0 = (blockIdx.x * 7 + blockIdx.y * 3 + blockIdx.z) & 15;
  f32x4 acc[4][4] = {};
  gemm_mainloop((const char*)A, (const char*)Wt, (char*)As, (char*)Bs,
                m0, n0, tid, t0, acc);
#pragma unroll
  for (int mi = 0; mi < 4; mi++) {
#pragma unroll
    for (int c = 0; c < 4; c++) {
      const int n = n0 + wc * 64 + c * 16 + ln;
      const float bv_ = bias[n];
      const int h = n >> 6, d = n & 63;
      const int mbase = m0 + wr * 64 + mi * 16 + lh * 4;
      if (z < 2) {
#pragma unroll
        for (int r = 0; r < 4; r++) {
          int m = mbase + r, b = m >> 11, s = m & (S_LEN - 1);
          out[((size_t)(b * NH + h) * S_LEN + s) * DEPTH + d] =
              b16((acc[mi][c][r] + bv_) * scale);
        }
      } else {  // V^T [B,H,d,S]
        const int b = mbase >> 11, s = mbase & (S_LEN - 1);
        us4 pk;
#pragma unroll
        for (int r = 0; r < 4; r++) pk[r] = b16(acc[mi][c][r] + bv_);
        *(us4*)&out[((size_t)(b * NH + h) * DEPTH + d) * S_LEN + s] = pk;
      }
    }
  }
}

// ------------- final projection GEMM: f32 out, 64x128 tile -----------------
// R17: grid (64,8) = 512 blocks = 2 blocks/CU (vs 128x128's 256 = 1/CU =
// 1 wave/SIMD, zero TLP to hide LDS/staging latency).
__global__ __launch_bounds__(256) void gemm_out_k(
    const unsigned short* __restrict__ A, const unsigned short* __restrict__ Wt,
    const float* __restrict__ bias, float* __restrict__ out) {
  __shared__ unsigned short As[2 * 64 * 64];   // 16 KB
  __shared__ unsigned short Bs[2 * 128 * 64];  // 32 KB
  char* AsB = (char*)As;
  char* BsB = (char*)Bs;
  const int m0 = blockIdx.x * 64, n0 = blockIdx.y * 128;
  const int tid = threadIdx.x, lane = tid & 63, w = tid >> 6;
  const int ln = lane & 15, lh = lane >> 4;
  const int wr = w >> 1, wc = w & 1;
  const int t0 = (blockIdx.x * 7 + blockIdx.y * 3) & 15;
  const char* Ab = (const char*)A;
  const char* Bb = (const char*)Wt;
  f32x4 acc[2][4] = {};
  stage64a(Ab, m0, t0 * 128, AsB, tid);
  stage128<2048>(Bb, n0, t0 * 128, BsB, tid);
  __syncthreads();
  for (int i = 0; i < 16; i++) {
    const int curA = (i & 1) << 13, curB = (i & 1) << 14;
    if (i < 15) {
      const int kb = ((t0 + i + 1) & 15) * 128;
      stage64a(Ab, m0, kb, AsB + (curA ^ (1 << 13)), tid);
      stage128<2048>(Bb, n0, kb, BsB + (curB ^ (1 << 14)), tid);
    }
#pragma unroll
    for (int ks = 0; ks < 2; ks++) {
      us8 af[2], bf[4];
#pragma unroll
      for (int mi = 0; mi < 2; mi++)
        af[mi] = SWZ_RD(AsB + curA, wr * 32 + mi * 16 + ln, ks * 4 + lh);
#pragma unroll
      for (int c = 0; c < 4; c++)
        bf[c] = SWZ_RD(BsB + curB, wc * 64 + c * 16 + ln, ks * 4 + lh);
#pragma unroll
      for (int mi = 0; mi < 2; mi++)
#pragma unroll
        for (int c = 0; c < 4; c++)
          acc[mi][c] = mfma16(af[mi], bf[c], acc[mi][c]);
    }
    __syncthreads();
  }
#pragma unroll
  for (int mi = 0; mi < 2; mi++) {
#pragma unroll
    for (int c = 0; c < 4; c++) {
      const int n = n0 + wc * 64 + c * 16 + ln;
      const float bv_ = bias[n];
      const int mbase = m0 + wr * 32 + mi * 16 + lh * 4;
#pragma unroll
      for (int r = 0; r < 4; r++)
        out[(size_t)(mbase + r) * DM + n] = acc[mi][c][r] + bv_;
    }
  }
}

// ---------------- attention: swapped QK^T, two-pass softmax, dbuf K ---------
// R17 base (280.0 us) + T5 setprio around MFMA clusters (R20): 5 blocks/CU at
// different qt-rotation phases -> wave role diversity -> setprio can arbitrate
// (m191 attn regime; null only in lockstep GEMMs per m190).
// Pass 2: qt-rotated tile order (R12), normal stores (R13), vmcnt(8)+s_barrier
// (R16, T4 discipline).
__global__ __launch_bounds__(256) void attn_k(const unsigned short* __restrict__ Qh,
    const unsigned short* __restrict__ Kh, const unsigned short* __restrict__ Vt,
    float* __restrict__ Wout, unsigned short* __restrict__ attnOut) {
  __shared__ unsigned short Ks[2 * 128 * 64];  // 32 KB, dbuf swizzled linear
  char* KsB = (char*)Ks;
  const int flat = blockIdx.x;
  const int xcd = flat & 7, g = flat >> 3;
  const int qt = g & 31;
  const int bh = xcd + 8 * (g >> 5);
  const int tid = threadIdx.x, w = tid >> 6, lane = tid & 63;
  const int ln = lane & 15, lh = lane >> 4;
  const int q0 = qt * 64;
  const unsigned short* Qb = Qh + (size_t)bh * S_LEN * DEPTH;
  const char* KbB = (const char*)(Kh + (size_t)bh * S_LEN * DEPTH);
  const unsigned short* Vb = Vt + (size_t)bh * DEPTH * S_LEN;
  // Q fragment (B-operand): n = q-row = ln, k = depth
  const int qrow = q0 + w * 16 + ln;
  const us8 qf0 = *(const us8*)(Qb + (size_t)qrow * DEPTH + lh * 8);
  const us8 qf1 = *(const us8*)(Qb + (size_t)qrow * DEPTH + 32 + lh * 8);

  // ---- pass 1: l = sum over keys of exp2(score') for q-row ln ----
  float l = 0.f;
  stage128k(KbB, 0, KsB, tid);
  __syncthreads();
  for (int t = 0; t < 16; t++) {
    const int cur = (t & 1) << 14, nxt = cur ^ (1 << 14);
    if (t < 15) stage128k(KbB, (t + 1) * 128, KsB + nxt, tid);
#pragma unroll
    for (int kt2 = 0; kt2 < 4; kt2++) {
      const int r0 = kt2 * 32 + ln;
      f32x4 d0 = {0.f, 0.f, 0.f, 0.f}, d1 = {0.f, 0.f, 0.f, 0.f};
      __builtin_amdgcn_s_setprio(1);
      d0 = mfma16(SWZ_RD(KsB + cur, r0, lh), qf0, d0);
      d0 = mfma16(SWZ_RD(KsB + cur, r0, 4 + lh), qf1, d0);
      d1 = mfma16(SWZ_RD(KsB + cur, r0 + 16, lh), qf0, d1);
      d1 = mfma16(SWZ_RD(KsB + cur, r0 + 16, 4 + lh), qf1, d1);
      __builtin_amdgcn_s_setprio(0);
      l += (ex2(d0[0]) + ex2(d0[1])) + (ex2(d0[2]) + ex2(d0[3])) +
           (ex2(d1[0]) + ex2(d1[1])) + (ex2(d1[2]) + ex2(d1[3]));
    }
    __syncthreads();
  }
  l += __shfl_xor(l, 16);
  l += __shfl_xor(l, 32);
  const float rl = 1.0f / l;

  // ---- pass 2: qt-rotated t-order; weights -> d_out, PV accumulate ----
  f32x4 o[4] = {};
  float* Wr = Wout + (size_t)bh * S_LEN * S_LEN + (size_t)(q0 + w * 16 + ln) * S_LEN;
  const int t0 = qt & 15;
  stage128k(KbB, t0 * 128, KsB, tid);
  __syncthreads();
  for (int i = 0; i < 16; i++) {
    const int t = (t0 + i) & 15;
    const int cur = (i & 1) << 14, nxt = cur ^ (1 << 14);
    if (i < 15) stage128k(KbB, ((t0 + i + 1) & 15) * 128, KsB + nxt, tid);
    __builtin_amdgcn_sched_barrier(0);  // staging loads issue first (oldest in vmcnt FIFO)
    const int sc = t * 128;
#pragma unroll
    for (int kt2 = 0; kt2 < 4; kt2++) {
      const int r0 = kt2 * 32 + ln;
      f32x4 d0 = {0.f, 0.f, 0.f, 0.f}, d1 = {0.f, 0.f, 0.f, 0.f};
      __builtin_amdgcn_s_setprio(1);
      d0 = mfma16(SWZ_RD(KsB + cur, r0, lh), qf0, d0);
      d0 = mfma16(SWZ_RD(KsB + cur, r0, 4 + lh), qf1, d0);
      d1 = mfma16(SWZ_RD(KsB + cur, r0 + 16, lh), qf0, d1);
      d1 = mfma16(SWZ_RD(KsB + cur, r0 + 16, 4 + lh), qf1, d1);
      __builtin_amdgcn_s_setprio(0);
      // lane owns q-row ln, keys sc + kt2*32 + 8*lh + {0..7}
      f32x4 w0, w1;
#pragma unroll
      for (int r = 0; r < 4; r++) {
        w0[r] = ex2(d0[r]) * rl;
        w1[r] = ex2(d1[r]) * rl;
      }
      *(f32x4*)(Wr + sc + kt2 * 32 + 8 * lh) = w0;
      *(f32x4*)(Wr + sc + kt2 * 32 + 8 * lh + 4) = w1;
      // bf16 pack IS the PV A-fragment (row ln, keys 8lh..8lh+7)
      us8 af;
      af[0] = b16(w0[0]); af[1] = b16(w0[1]);
      af[2] = b16(w0[2]); af[3] = b16(w0[3]);
      af[4] = b16(w1[0]); af[5] = b16(w1[1]);
      af[6] = b16(w1[2]); af[7] = b16(w1[3]);
      __builtin_amdgcn_s_setprio(1);
#pragma unroll
      for (int dt = 0; dt < 4; dt++) {
        us8 vf = *(const us8*)(Vb + (size_t)(dt * 16 + ln) * S_LEN + sc +
                               kt2 * 32 + lh * 8);
        o[dt] = mfma16(af, vf, o[dt]);
      }
      __builtin_amdgcn_s_setprio(0);
    }
    // staging (oldest 4 VMEM ops) retired; up to 8 weight stores stay in flight
    asm volatile("s_waitcnt vmcnt(8)" ::: "memory");
    __builtin_amdgcn_s_barrier();
  }

  const int b = bh >> 4, h = bh & 15;
#pragma unroll
  for (int dt = 0; dt < 4; dt++) {
#pragma unroll
    for (int r = 0; r < 4; r++) {
      size_t row = (size_t)b * S_LEN + q0 + w * 16 + lh * 4 + r;
      attnOut[row * DM + h * DEPTH + dt * 16 + ln] = b16(o[dt][r]);
    }
  }
}

extern "C" void kernel_launch(void* const* d_in, const int* in_sizes, int n_in,
                              void* d_out, int out_size, void* d_ws, size_t ws_size,
                              hipStream_t stream) {
  const float* queries = (const float*)d_in[0];
  const float* keys    = (const float*)d_in[1];
  const float* values  = (const float*)d_in[2];
  const float* wq = (const float*)d_in[3];
  const float* bq = (const float*)d_in[4];
  const float* wk = (const float*)d_in[5];
  const float* bk = (const float*)d_in[6];
  const float* wv = (const float*)d_in[7];
  const float* bv = (const float*)d_in[8];
  const float* wo = (const float*)d_in[9];
  const float* bo = (const float*)d_in[10];

  float* out = (float*)d_out;
  float* wts = out + (size_t)BATCH * S_LEN * DM;  // weights output after `out`

  char* ws = (char*)d_ws;
  const size_t WSZ = (size_t)DM * DM * sizeof(unsigned short);            // 2 MB
  const size_t TSZ = (size_t)BATCH * S_LEN * DM * sizeof(unsigned short); // 8 MB
  unsigned short* Wqt = (unsigned short*)(ws + 0 * WSZ);
  unsigned short* Wkt = (unsigned short*)(ws + 1 * WSZ);
  unsigned short* Wvt = (unsigned short*)(ws + 2 * WSZ);
  unsigned short* Wot = (unsigned short*)(ws + 3 * WSZ);
  unsigned short* Qbf = (unsigned short*)(ws + 4 * WSZ + 0 * TSZ);
  unsigned short* Kbf = (unsigned short*)(ws + 4 * WSZ + 1 * TSZ);
  unsigned short* Vbf = (unsigned short*)(ws + 4 * WSZ + 2 * TSZ);
  unsigned short* Qhd = (unsigned short*)(ws + 4 * WSZ + 3 * TSZ);
  unsigned short* Khd = (unsigned short*)(ws + 4 * WSZ + 4 * TSZ);
  unsigned short* Vtd = (unsigned short*)(ws + 4 * WSZ + 5 * TSZ);
  unsigned short* attn = Qbf;  // Qbf dead after Q-projection; reuse for attn out

  cvt3_k<<<dim3(2048, 3), 256, 0, stream>>>(queries, keys, values, Qbf, Kbf, Vbf);
  transpose_w4_k<<<dim3(32, 32, 4), 256, 0, stream>>>(wq, wk, wv, wo,
                                                      Wqt, Wkt, Wvt, Wot);
  gemm_qkv_k<<<dim3(32, 8, 3), 256, 0, stream>>>(Qbf, Kbf, Vbf, Wqt, Wkt, Wvt,
                                                 bq, bk, bv, Qhd, Khd, Vtd,
                                                 0.125f * LOG2E);
  attn_k<<<1024, 256, 0, stream>>>(Qhd, Khd, Vtd, wts, attn);
  gemm_out_k<<<dim3(64, 8), 256, 0, stream>>>(attn, Wot, bo, out);
}

// Round 21
// 278.589 us; speedup vs baseline: 1.3389x; 1.0158x over previous
//
#include <hip/hip_runtime.h>
#include <hip/hip_bf16.h>

#define DM 1024
#define S_LEN 2048
#define NH 16
#define DEPTH 64
#define BATCH 2
#define LOG2E 1.4426950408889634f

typedef float f32x4 __attribute__((ext_vector_type(4)));
typedef __bf16 bf16x8 __attribute__((ext_vector_type(8)));
typedef unsigned short us8 __attribute__((ext_vector_type(8)));
typedef unsigned short us4 __attribute__((ext_vector_type(4)));

__device__ __forceinline__ unsigned short b16(float f) {
  return __builtin_bit_cast(unsigned short, (__bf16)f);
}
__device__ __forceinline__ float ex2(float x) {
#if __has_builtin(__builtin_amdgcn_exp2f)
  return __builtin_amdgcn_exp2f(x);
#else
  return exp2f(x);
#endif
}
__device__ __forceinline__ f32x4 mfma16(us8 a, us8 b, f32x4 c) {
  return __builtin_amdgcn_mfma_f32_16x16x32_bf16(
      __builtin_bit_cast(bf16x8, a), __builtin_bit_cast(bf16x8, b), c, 0, 0, 0);
}
// async global->LDS, 16B per lane; LDS dest = wave-uniform base (+lane*16 by HW)
__device__ __forceinline__ void gll16(const void* g, void* l) {
  __builtin_amdgcn_global_load_lds(
      (const __attribute__((address_space(1))) void*)g,
      (__attribute__((address_space(3))) void*)l, 16, 0, 0);
}
// swizzled LDS read: 16B chunk c of row r lives at slot c^(r&7); rows are 128B
#define SWZ_RD(baseB, r, c) \
  (*(const us8*)((baseB) + (size_t)(r) * 128 + ((((c) ^ ((r) & 7))) << 4)))

// stage a 128-row x 128B tile (global rows r0.., row stride RSB bytes) into LDS
// dst, inverse-swizzled source so SWZ_RD sees chunk^(row&7). 4 gll16/thread.
template <int RSB>
__device__ __forceinline__ void stage128(const char* Gb, int r0, int kb,
                                         char* dst, int tid) {
#pragma unroll
  for (int i = 0; i < 4; i++) {
    int t16 = i * 256 + tid;
    int row = t16 >> 3;
    int g = (t16 & 7) ^ (row & 7);
    gll16(Gb + (size_t)(r0 + row) * RSB + kb + (g << 4),
          dst + i * 4096 + (tid & ~63) * 16);
  }
}

// 64-row x 128B tile (row stride 2048B): 2 gll16/thread = 8 KB.
__device__ __forceinline__ void stage64a(const char* Gb, int r0, int kb,
                                         char* dst, int tid) {
#pragma unroll
  for (int i = 0; i < 2; i++) {
    int t16 = i * 256 + tid;
    int row = t16 >> 3;
    int g = (t16 & 7) ^ (row & 7);
    gll16(Gb + (size_t)(r0 + row) * 2048 + kb + (g << 4),
          dst + i * 4096 + (tid & ~63) * 16);
  }
}

// K staging (128 rows) with per-32-row-block sigma permutation: LDS row i holds
// key sigma(i) so QK^T's C/D lane mapping directly yields PV A-fragment key
// order (keys 8*lh..8*lh+7 per lane).
__device__ __forceinline__ void stage128k(const char* Gb, int r0, char* dst,
                                          int tid) {
#pragma unroll
  for (int i = 0; i < 4; i++) {
    int t16 = i * 256 + tid;
    int row = t16 >> 3;
    int g = (t16 & 7) ^ (row & 7);
    int i5 = row & 31, jj = i5 & 15, hi = i5 >> 4;
    int prow = (row & 96) | ((jj >> 2) << 3) | (hi << 2) | (jj & 3);
    gll16(Gb + (size_t)(r0 + prow) * 128 + (g << 4),
          dst + i * 4096 + (tid & ~63) * 16);
  }
}

// ------- prep: fused f32->bf16 activation convert + weight transposes -------
// y in {0,1,2}: cvt q/k/v (x over 2048 blocks, 2048 elems each)
// y in {3..6}:  Wt[n][k] = bf16(W[k][n]) for wq/wk/wv/wo (x = ti*32+tj, 1024)
__global__ __launch_bounds__(256) void prep_k(
    const float* __restrict__ q, const float* __restrict__ k,
    const float* __restrict__ v, unsigned short* __restrict__ oq,
    unsigned short* __restrict__ ok, unsigned short* __restrict__ ov,
    const float* __restrict__ w0, const float* __restrict__ w1,
    const float* __restrict__ w2, const float* __restrict__ w3,
    unsigned short* __restrict__ t0, unsigned short* __restrict__ t1,
    unsigned short* __restrict__ t2, unsigned short* __restrict__ t3) {
  const int y = blockIdx.y;
  if (y < 3) {
    const float* src = y == 0 ? q : y == 1 ? k : v;
    unsigned short* dst = y == 0 ? oq : y == 1 ? ok : ov;
    size_t i = ((size_t)blockIdx.x * 256 + threadIdx.x) * 8;
    float4 f0 = *(const float4*)(src + i);
    float4 f1 = *(const float4*)(src + i + 4);
    us8 o;
    o[0] = b16(f0.x); o[1] = b16(f0.y); o[2] = b16(f0.z); o[3] = b16(f0.w);
    o[4] = b16(f1.x); o[5] = b16(f1.y); o[6] = b16(f1.z); o[7] = b16(f1.w);
    *(us8*)(dst + i) = o;
  } else {
    if (blockIdx.x >= 1024) return;
    const int z = y - 3;
    const float* W = z == 0 ? w0 : z == 1 ? w1 : z == 2 ? w2 : w3;
    unsigned short* Wt = z == 0 ? t0 : z == 1 ? t1 : z == 2 ? t2 : t3;
    __shared__ float tile[32][33];
    const int ti = blockIdx.x >> 5, tj = blockIdx.x & 31;
    const int c = threadIdx.x & 31, r8 = threadIdx.x >> 5;
#pragma unroll
    for (int i = 0; i < 4; i++) {
      int r = r8 * 4 + i;
      tile[r][c] = W[(size_t)(ti * 32 + r) * DM + tj * 32 + c];
    }
    __syncthreads();
#pragma unroll
    for (int i = 0; i < 4; i++) {
      int r = r8 * 4 + i;
      Wt[(size_t)(tj * 32 + r) * DM + ti * 32 + c] = b16(tile[c][r]);
    }
  }
}

// ---- shared GEMM main loop: 128x128 tile, BK=64, dbuf LDS, 2-phase pipeline -
// K-steps swept in per-block ROTATED order (start t0): tile row stride 2048B
// aliases the 8KB HBM channel period (only 4/32 channel groups per k-phase),
// so lockstep blocks queue on the same channels; rotation spreads them.
__device__ __forceinline__ void gemm_mainloop(const char* Ab, const char* Bb,
    char* AsB, char* BsB, int m0, int n0, int tid, int t0,
    f32x4 (&acc)[4][4]) {
  const int lane = tid & 63, w = tid >> 6;
  const int ln = lane & 15, lh = lane >> 4;
  const int wr = w >> 1, wc = w & 1;
  stage128<2048>(Ab, m0, t0 * 128, AsB, tid);
  stage128<2048>(Bb, n0, t0 * 128, BsB, tid);
  __syncthreads();
  for (int i = 0; i < 16; i++) {
    const int cur = (i & 1) << 14, nxt = cur ^ (1 << 14);
    if (i < 15) {
      const int kb = (((t0 + i + 1) & 15)) * 128;
      stage128<2048>(Ab, m0, kb, AsB + nxt, tid);
      stage128<2048>(Bb, n0, kb, BsB + nxt, tid);
    }
#pragma unroll
    for (int ks = 0; ks < 2; ks++) {
      us8 af[4], bf[4];
#pragma unroll
      for (int mi = 0; mi < 4; mi++)
        af[mi] = SWZ_RD(AsB + cur, wr * 64 + mi * 16 + ln, ks * 4 + lh);
#pragma unroll
      for (int c = 0; c < 4; c++)
        bf[c] = SWZ_RD(BsB + cur, wc * 64 + c * 16 + ln, ks * 4 + lh);
#pragma unroll
      for (int mi = 0; mi < 4; mi++)
#pragma unroll
        for (int c = 0; c < 4; c++)
          acc[mi][c] = mfma16(af[mi], bf[c], acc[mi][c]);
    }
    __syncthreads();
  }
}

// -------- fused Q/K/V projection GEMM (blockIdx.z selects which) ------------
__global__ __launch_bounds__(256) void gemm_qkv_k(
    const unsigned short* __restrict__ Aq, const unsigned short* __restrict__ Ak,
    const unsigned short* __restrict__ Av, const unsigned short* __restrict__ Wq,
    const unsigned short* __restrict__ Wk, const unsigned short* __restrict__ Wv,
    const float* __restrict__ bq, const float* __restrict__ bk,
    const float* __restrict__ bv, unsigned short* __restrict__ oq,
    unsigned short* __restrict__ ok, unsigned short* __restrict__ ov,
    float qscale) {
  __shared__ unsigned short As[2 * 128 * 64];  // 32 KB
  __shared__ unsigned short Bs[2 * 128 * 64];  // 32 KB
  const int z = blockIdx.z;
  const unsigned short* A = z == 0 ? Aq : z == 1 ? Ak : Av;
  const unsigned short* Wt = z == 0 ? Wq : z == 1 ? Wk : Wv;
  const float* bias = z == 0 ? bq : z == 1 ? bk : bv;
  unsigned short* out = z == 0 ? oq : z == 1 ? ok : ov;
  const float scale = z == 0 ? qscale : 1.0f;
  const int m0 = blockIdx.x * 128, n0 = blockIdx.y * 128;
  const int tid = threadIdx.x, lane = tid & 63, w = tid >> 6;
  const int ln = lane & 15, lh = lane >> 4;
  const int wr = w >> 1, wc = w & 1;
  const int t0 = (blockIdx.x * 7 + blockIdx.y * 3 + blockIdx.z) & 15;
  f32x4 acc[4][4] = {};
  gemm_mainloop((const char*)A, (const char*)Wt, (char*)As, (char*)Bs,
                m0, n0, tid, t0, acc);
#pragma unroll
  for (int mi = 0; mi < 4; mi++) {
#pragma unroll
    for (int c = 0; c < 4; c++) {
      const int n = n0 + wc * 64 + c * 16 + ln;
      const float bv_ = bias[n];
      const int h = n >> 6, d = n & 63;
      const int mbase = m0 + wr * 64 + mi * 16 + lh * 4;
      if (z < 2) {
#pragma unroll
        for (int r = 0; r < 4; r++) {
          int m = mbase + r, b = m >> 11, s = m & (S_LEN - 1);
          out[((size_t)(b * NH + h) * S_LEN + s) * DEPTH + d] =
              b16((acc[mi][c][r] + bv_) * scale);
        }
      } else {  // V^T [B,H,d,S]
        const int b = mbase >> 11, s = mbase & (S_LEN - 1);
        us4 pk;
#pragma unroll
        for (int r = 0; r < 4; r++) pk[r] = b16(acc[mi][c][r] + bv_);
        *(us4*)&out[((size_t)(b * NH + h) * DEPTH + d) * S_LEN + s] = pk;
      }
    }
  }
}

// ------------- final projection GEMM: f32 out, 64x128 tile -----------------
// R17: grid (64,8) = 512 blocks = 2 blocks/CU (vs 128x128's 256 = 1/CU =
// 1 wave/SIMD, zero TLP to hide LDS/staging latency).
__global__ __launch_bounds__(256) void gemm_out_k(
    const unsigned short* __restrict__ A, const unsigned short* __restrict__ Wt,
    const float* __restrict__ bias, float* __restrict__ out) {
  __shared__ unsigned short As[2 * 64 * 64];   // 16 KB
  __shared__ unsigned short Bs[2 * 128 * 64];  // 32 KB
  char* AsB = (char*)As;
  char* BsB = (char*)Bs;
  const int m0 = blockIdx.x * 64, n0 = blockIdx.y * 128;
  const int tid = threadIdx.x, lane = tid & 63, w = tid >> 6;
  const int ln = lane & 15, lh = lane >> 4;
  const int wr = w >> 1, wc = w & 1;
  const int t0 = (blockIdx.x * 7 + blockIdx.y * 3) & 15;
  const char* Ab = (const char*)A;
  const char* Bb = (const char*)Wt;
  f32x4 acc[2][4] = {};
  stage64a(Ab, m0, t0 * 128, AsB, tid);
  stage128<2048>(Bb, n0, t0 * 128, BsB, tid);
  __syncthreads();
  for (int i = 0; i < 16; i++) {
    const int curA = (i & 1) << 13, curB = (i & 1) << 14;
    if (i < 15) {
      const int kb = ((t0 + i + 1) & 15) * 128;
      stage64a(Ab, m0, kb, AsB + (curA ^ (1 << 13)), tid);
      stage128<2048>(Bb, n0, kb, BsB + (curB ^ (1 << 14)), tid);
    }
#pragma unroll
    for (int ks = 0; ks < 2; ks++) {
      us8 af[2], bf[4];
#pragma unroll
      for (int mi = 0; mi < 2; mi++)
        af[mi] = SWZ_RD(AsB + curA, wr * 32 + mi * 16 + ln, ks * 4 + lh);
#pragma unroll
      for (int c = 0; c < 4; c++)
        bf[c] = SWZ_RD(BsB + curB, wc * 64 + c * 16 + ln, ks * 4 + lh);
#pragma unroll
      for (int mi = 0; mi < 2; mi++)
#pragma unroll
        for (int c = 0; c < 4; c++)
          acc[mi][c] = mfma16(af[mi], bf[c], acc[mi][c]);
    }
    __syncthreads();
  }
#pragma unroll
  for (int mi = 0; mi < 2; mi++) {
#pragma unroll
    for (int c = 0; c < 4; c++) {
      const int n = n0 + wc * 64 + c * 16 + ln;
      const float bv_ = bias[n];
      const int mbase = m0 + wr * 32 + mi * 16 + lh * 4;
#pragma unroll
      for (int r = 0; r < 4; r++)
        out[(size_t)(mbase + r) * DM + n] = acc[mi][c][r] + bv_;
    }
  }
}

// ---------------- attention: swapped QK^T, two-pass softmax, dbuf K ---------
// Pass 2: per-block ROTATED key-tile order keyed by qt (R12: de-aliases the
// 8 KB row-stride weights stream across HBM channels; key must maximize phase
// diversity among co-resident blocks -- by-bh regressed). Normal stores (R13:
// nt bypasses L2 write-combining, +22us). Loop-end: s_waitcnt vmcnt(8) +
// s_barrier -- staging loads retire, weight stores stay in flight (R16, T4).
__global__ __launch_bounds__(256) void attn_k(const unsigned short* __restrict__ Qh,
    const unsigned short* __restrict__ Kh, const unsigned short* __restrict__ Vt,
    float* __restrict__ Wout, unsigned short* __restrict__ attnOut) {
  __shared__ unsigned short Ks[2 * 128 * 64];  // 32 KB, dbuf swizzled linear
  char* KsB = (char*)Ks;
  const int flat = blockIdx.x;
  const int xcd = flat & 7, g = flat >> 3;
  const int qt = g & 31;
  const int bh = xcd + 8 * (g >> 5);
  const int tid = threadIdx.x, w = tid >> 6, lane = tid & 63;
  const int ln = lane & 15, lh = lane >> 4;
  const int q0 = qt * 64;
  const unsigned short* Qb = Qh + (size_t)bh * S_LEN * DEPTH;
  const char* KbB = (const char*)(Kh + (size_t)bh * S_LEN * DEPTH);
  const unsigned short* Vb = Vt + (size_t)bh * DEPTH * S_LEN;
  // Q fragment (B-operand): n = q-row = ln, k = depth
  const int qrow = q0 + w * 16 + ln;
  const us8 qf0 = *(const us8*)(Qb + (size_t)qrow * DEPTH + lh * 8);
  const us8 qf1 = *(const us8*)(Qb + (size_t)qrow * DEPTH + 32 + lh * 8);

  // ---- pass 1: l = sum over keys of exp2(score') for q-row ln ----
  float l = 0.f;
  stage128k(KbB, 0, KsB, tid);
  __syncthreads();
  for (int t = 0; t < 16; t++) {
    const int cur = (t & 1) << 14, nxt = cur ^ (1 << 14);
    if (t < 15) stage128k(KbB, (t + 1) * 128, KsB + nxt, tid);
#pragma unroll
    for (int kt2 = 0; kt2 < 4; kt2++) {
      const int r0 = kt2 * 32 + ln;
      f32x4 d0 = {0.f, 0.f, 0.f, 0.f}, d1 = {0.f, 0.f, 0.f, 0.f};
      d0 = mfma16(SWZ_RD(KsB + cur, r0, lh), qf0, d0);
      d0 = mfma16(SWZ_RD(KsB + cur, r0, 4 + lh), qf1, d0);
      d1 = mfma16(SWZ_RD(KsB + cur, r0 + 16, lh), qf0, d1);
      d1 = mfma16(SWZ_RD(KsB + cur, r0 + 16, 4 + lh), qf1, d1);
      l += (ex2(d0[0]) + ex2(d0[1])) + (ex2(d0[2]) + ex2(d0[3])) +
           (ex2(d1[0]) + ex2(d1[1])) + (ex2(d1[2]) + ex2(d1[3]));
    }
    __syncthreads();
  }
  l += __shfl_xor(l, 16);
  l += __shfl_xor(l, 32);
  const float rl = 1.0f / l;

  // ---- pass 2: qt-rotated t-order; weights -> d_out, PV accumulate ----
  f32x4 o[4] = {};
  float* Wr = Wout + (size_t)bh * S_LEN * S_LEN + (size_t)(q0 + w * 16 + ln) * S_LEN;
  const int t0 = qt & 15;
  stage128k(KbB, t0 * 128, KsB, tid);
  __syncthreads();
  for (int i = 0; i < 16; i++) {
    const int t = (t0 + i) & 15;
    const int cur = (i & 1) << 14, nxt = cur ^ (1 << 14);
    if (i < 15) stage128k(KbB, ((t0 + i + 1) & 15) * 128, KsB + nxt, tid);
    __builtin_amdgcn_sched_barrier(0);  // staging loads issue first (oldest in vmcnt FIFO)
    const int sc = t * 128;
#pragma unroll
    for (int kt2 = 0; kt2 < 4; kt2++) {
      const int r0 = kt2 * 32 + ln;
      f32x4 d0 = {0.f, 0.f, 0.f, 0.f}, d1 = {0.f, 0.f, 0.f, 0.f};
      d0 = mfma16(SWZ_RD(KsB + cur, r0, lh), qf0, d0);
      d0 = mfma16(SWZ_RD(KsB + cur, r0, 4 + lh), qf1, d0);
      d1 = mfma16(SWZ_RD(KsB + cur, r0 + 16, lh), qf0, d1);
      d1 = mfma16(SWZ_RD(KsB + cur, r0 + 16, 4 + lh), qf1, d1);
      // lane owns q-row ln, keys sc + kt2*32 + 8*lh + {0..7}
      f32x4 w0, w1;
#pragma unroll
      for (int r = 0; r < 4; r++) {
        w0[r] = ex2(d0[r]) * rl;
        w1[r] = ex2(d1[r]) * rl;
      }
      *(f32x4*)(Wr + sc + kt2 * 32 + 8 * lh) = w0;
      *(f32x4*)(Wr + sc + kt2 * 32 + 8 * lh + 4) = w1;
      // bf16 pack IS the PV A-fragment (row ln, keys 8lh..8lh+7)
      us8 af;
      af[0] = b16(w0[0]); af[1] = b16(w0[1]);
      af[2] = b16(w0[2]); af[3] = b16(w0[3]);
      af[4] = b16(w1[0]); af[5] = b16(w1[1]);
      af[6] = b16(w1[2]); af[7] = b16(w1[3]);
#pragma unroll
      for (int dt = 0; dt < 4; dt++) {
        us8 vf = *(const us8*)(Vb + (size_t)(dt * 16 + ln) * S_LEN + sc +
                               kt2 * 32 + lh * 8);
        o[dt] = mfma16(af, vf, o[dt]);
      }
    }
    // staging (oldest 4 VMEM ops) retired; up to 8 weight stores stay in flight
    asm volatile("s_waitcnt vmcnt(8)" ::: "memory");
    __builtin_amdgcn_s_barrier();
  }

  const int b = bh >> 4, h = bh & 15;
#pragma unroll
  for (int dt = 0; dt < 4; dt++) {
#pragma unroll
    for (int r = 0; r < 4; r++) {
      size_t row = (size_t)b * S_LEN + q0 + w * 16 + lh * 4 + r;
      attnOut[row * DM + h * DEPTH + dt * 16 + ln] = b16(o[dt][r]);
    }
  }
}

extern "C" void kernel_launch(void* const* d_in, const int* in_sizes, int n_in,
                              void* d_out, int out_size, void* d_ws, size_t ws_size,
                              hipStream_t stream) {
  const float* queries = (const float*)d_in[0];
  const float* keys    = (const float*)d_in[1];
  const float* values  = (const float*)d_in[2];
  const float* wq = (const float*)d_in[3];
  const float* bq = (const float*)d_in[4];
  const float* wk = (const float*)d_in[5];
  const float* bk = (const float*)d_in[6];
  const float* wv = (const float*)d_in[7];
  const float* bv = (const float*)d_in[8];
  const float* wo = (const float*)d_in[9];
  const float* bo = (const float*)d_in[10];

  float* out = (float*)d_out;
  float* wts = out + (size_t)BATCH * S_LEN * DM;  // weights output after `out`

  char* ws = (char*)d_ws;
  const size_t WSZ = (size_t)DM * DM * sizeof(unsigned short);            // 2 MB
  const size_t TSZ = (size_t)BATCH * S_LEN * DM * sizeof(unsigned short); // 8 MB
  unsigned short* Wqt = (unsigned short*)(ws + 0 * WSZ);
  unsigned short* Wkt = (unsigned short*)(ws + 1 * WSZ);
  unsigned short* Wvt = (unsigned short*)(ws + 2 * WSZ);
  unsigned short* Wot = (unsigned short*)(ws + 3 * WSZ);
  unsigned short* Qbf = (unsigned short*)(ws + 4 * WSZ + 0 * TSZ);
  unsigned short* Kbf = (unsigned short*)(ws + 4 * WSZ + 1 * TSZ);
  unsigned short* Vbf = (unsigned short*)(ws + 4 * WSZ + 2 * TSZ);
  unsigned short* Qhd = (unsigned short*)(ws + 4 * WSZ + 3 * TSZ);
  unsigned short* Khd = (unsigned short*)(ws + 4 * WSZ + 4 * TSZ);
  unsigned short* Vtd = (unsigned short*)(ws + 4 * WSZ + 5 * TSZ);
  unsigned short* attn = Qbf;  // Qbf dead after Q-projection; reuse for attn out

  prep_k<<<dim3(2048, 7), 256, 0, stream>>>(queries, keys, values,
                                            Qbf, Kbf, Vbf,
                                            wq, wk, wv, wo,
                                            Wqt, Wkt, Wvt, Wot);
  gemm_qkv_k<<<dim3(32, 8, 3), 256, 0, stream>>>(Qbf, Kbf, Vbf, Wqt, Wkt, Wvt,
                                                 bq, bk, bv, Qhd, Khd, Vtd,
                                                 0.125f * LOG2E);
  attn_k<<<1024, 256, 0, stream>>>(Qhd, Khd, Vtd, wts, attn);
  gemm_out_k<<<dim3(64, 8), 256, 0, stream>>>(attn, Wot, bo, out);
}

// Round 22
// 268.566 us; speedup vs baseline: 1.3889x; 1.0373x over previous
//
#include <hip/hip_runtime.h>
#include <hip/hip_bf16.h>

#define DM 1024
#define S_LEN 2048
#define NH 16
#define DEPTH 64
#define BATCH 2
#define LOG2E 1.4426950408889634f

typedef float f32x4 __attribute__((ext_vector_type(4)));
typedef __bf16 bf16x8 __attribute__((ext_vector_type(8)));
typedef unsigned short us8 __attribute__((ext_vector_type(8)));
typedef unsigned short us4 __attribute__((ext_vector_type(4)));

__device__ __forceinline__ unsigned short b16(float f) {
  return __builtin_bit_cast(unsigned short, (__bf16)f);
}
__device__ __forceinline__ float ex2(float x) {
#if __has_builtin(__builtin_amdgcn_exp2f)
  return __builtin_amdgcn_exp2f(x);
#else
  return exp2f(x);
#endif
}
__device__ __forceinline__ f32x4 mfma16(us8 a, us8 b, f32x4 c) {
  return __builtin_amdgcn_mfma_f32_16x16x32_bf16(
      __builtin_bit_cast(bf16x8, a), __builtin_bit_cast(bf16x8, b), c, 0, 0, 0);
}
// async global->LDS, 16B per lane; LDS dest = wave-uniform base (+lane*16 by HW)
__device__ __forceinline__ void gll16(const void* g, void* l) {
  __builtin_amdgcn_global_load_lds(
      (const __attribute__((address_space(1))) void*)g,
      (__attribute__((address_space(3))) void*)l, 16, 0, 0);
}
// swizzled LDS read: 16B chunk c of row r lives at slot c^(r&7); rows are 128B
#define SWZ_RD(baseB, r, c) \
  (*(const us8*)((baseB) + (size_t)(r) * 128 + ((((c) ^ ((r) & 7))) << 4)))

// stage a 128-row x 128B tile (global rows r0.., row stride RSB bytes) into LDS
// dst, inverse-swizzled source so SWZ_RD sees chunk^(row&7). 4 gll16/thread.
template <int RSB>
__device__ __forceinline__ void stage128(const char* Gb, int r0, int kb,
                                         char* dst, int tid) {
#pragma unroll
  for (int i = 0; i < 4; i++) {
    int t16 = i * 256 + tid;
    int row = t16 >> 3;
    int g = (t16 & 7) ^ (row & 7);
    gll16(Gb + (size_t)(r0 + row) * RSB + kb + (g << 4),
          dst + i * 4096 + (tid & ~63) * 16);
  }
}

// 64-row x 128B tile (row stride 2048B): 2 gll16/thread = 8 KB.
__device__ __forceinline__ void stage64a(const char* Gb, int r0, int kb,
                                         char* dst, int tid) {
#pragma unroll
  for (int i = 0; i < 2; i++) {
    int t16 = i * 256 + tid;
    int row = t16 >> 3;
    int g = (t16 & 7) ^ (row & 7);
    gll16(Gb + (size_t)(r0 + row) * 2048 + kb + (g << 4),
          dst + i * 4096 + (tid & ~63) * 16);
  }
}

// K staging (128 rows) with per-32-row-block sigma permutation: LDS row i holds
// key sigma(i) so QK^T's C/D lane mapping directly yields PV A-fragment key
// order (keys 8*lh..8*lh+7 per lane).
__device__ __forceinline__ void stage128k(const char* Gb, int r0, char* dst,
                                          int tid) {
#pragma unroll
  for (int i = 0; i < 4; i++) {
    int t16 = i * 256 + tid;
    int row = t16 >> 3;
    int g = (t16 & 7) ^ (row & 7);
    int i5 = row & 31, jj = i5 & 15, hi = i5 >> 4;
    int prow = (row & 96) | ((jj >> 2) << 3) | (hi << 2) | (jj & 3);
    gll16(Gb + (size_t)(r0 + prow) * 128 + (g << 4),
          dst + i * 4096 + (tid & ~63) * 16);
  }
}

// ------- prep: fused f32->bf16 activation convert + weight transposes -------
// y in {0,1,2}: cvt q/k/v (x over 2048 blocks, 2048 elems each)
// y in {3..6}:  Wt[n][k] = bf16(W[k][n]) for wq/wk/wv/wo (x = ti*32+tj, 1024)
__global__ __launch_bounds__(256) void prep_k(
    const float* __restrict__ q, const float* __restrict__ k,
    const float* __restrict__ v, unsigned short* __restrict__ oq,
    unsigned short* __restrict__ ok, unsigned short* __restrict__ ov,
    const float* __restrict__ w0, const float* __restrict__ w1,
    const float* __restrict__ w2, const float* __restrict__ w3,
    unsigned short* __restrict__ t0, unsigned short* __restrict__ t1,
    unsigned short* __restrict__ t2, unsigned short* __restrict__ t3) {
  const int y = blockIdx.y;
  if (y < 3) {
    const float* src = y == 0 ? q : y == 1 ? k : v;
    unsigned short* dst = y == 0 ? oq : y == 1 ? ok : ov;
    size_t i = ((size_t)blockIdx.x * 256 + threadIdx.x) * 8;
    float4 f0 = *(const float4*)(src + i);
    float4 f1 = *(const float4*)(src + i + 4);
    us8 o;
    o[0] = b16(f0.x); o[1] = b16(f0.y); o[2] = b16(f0.z); o[3] = b16(f0.w);
    o[4] = b16(f1.x); o[5] = b16(f1.y); o[6] = b16(f1.z); o[7] = b16(f1.w);
    *(us8*)(dst + i) = o;
  } else {
    if (blockIdx.x >= 1024) return;
    const int z = y - 3;
    const float* W = z == 0 ? w0 : z == 1 ? w1 : z == 2 ? w2 : w3;
    unsigned short* Wt = z == 0 ? t0 : z == 1 ? t1 : z == 2 ? t2 : t3;
    __shared__ float tile[32][33];
    const int ti = blockIdx.x >> 5, tj = blockIdx.x & 31;
    const int c = threadIdx.x & 31, r8 = threadIdx.x >> 5;
#pragma unroll
    for (int i = 0; i < 4; i++) {
      int r = r8 * 4 + i;
      tile[r][c] = W[(size_t)(ti * 32 + r) * DM + tj * 32 + c];
    }
    __syncthreads();
#pragma unroll
    for (int i = 0; i < 4; i++) {
      int r = r8 * 4 + i;
      Wt[(size_t)(tj * 32 + r) * DM + ti * 32 + c] = b16(tile[c][r]);
    }
  }
}

// ---- shared 64x128 GEMM main loop: BK=64, dbuf LDS, 2-phase pipeline -------
// A: 64 rows (stage64a, 16 KB dbuf), B: 128 rows (stage128, 32 KB dbuf) =
// 48 KB total -> 3 blocks/CU. K-steps swept in per-block ROTATED order (t0):
// row stride 2048B aliases the 8KB HBM channel period; rotation spreads the
// lockstep phases across channels (R14).
__device__ __forceinline__ void gemm_mainloop64(const char* Ab, const char* Bb,
    char* AsB, char* BsB, int m0, int n0, int tid, int t0,
    f32x4 (&acc)[2][4]) {
  const int lane = tid & 63, w = tid >> 6;
  const int ln = lane & 15, lh = lane >> 4;
  const int wr = w >> 1, wc = w & 1;
  stage64a(Ab, m0, t0 * 128, AsB, tid);
  stage128<2048>(Bb, n0, t0 * 128, BsB, tid);
  __syncthreads();
  for (int i = 0; i < 16; i++) {
    const int curA = (i & 1) << 13, curB = (i & 1) << 14;
    if (i < 15) {
      const int kb = ((t0 + i + 1) & 15) * 128;
      stage64a(Ab, m0, kb, AsB + (curA ^ (1 << 13)), tid);
      stage128<2048>(Bb, n0, kb, BsB + (curB ^ (1 << 14)), tid);
    }
#pragma unroll
    for (int ks = 0; ks < 2; ks++) {
      us8 af[2], bf[4];
#pragma unroll
      for (int mi = 0; mi < 2; mi++)
        af[mi] = SWZ_RD(AsB + curA, wr * 32 + mi * 16 + ln, ks * 4 + lh);
#pragma unroll
      for (int c = 0; c < 4; c++)
        bf[c] = SWZ_RD(BsB + curB, wc * 64 + c * 16 + ln, ks * 4 + lh);
#pragma unroll
      for (int mi = 0; mi < 2; mi++)
#pragma unroll
        for (int c = 0; c < 4; c++)
          acc[mi][c] = mfma16(af[mi], bf[c], acc[mi][c]);
    }
    __syncthreads();
  }
}

// -------- fused Q/K/V projection GEMM, 64x128 tile (z selects which) --------
// R22: 48 KB LDS -> 3 blocks/CU; grid (64,8,3) = 1536 = 6/CU = two clean
// full-GPU rounds (the 128x128 version's 64 KB -> 2/CU made 768 blocks run as
// 512 + a half-idle 256-block tail).
__global__ __launch_bounds__(256) void gemm_qkv_k(
    const unsigned short* __restrict__ Aq, const unsigned short* __restrict__ Ak,
    const unsigned short* __restrict__ Av, const unsigned short* __restrict__ Wq,
    const unsigned short* __restrict__ Wk, const unsigned short* __restrict__ Wv,
    const float* __restrict__ bq, const float* __restrict__ bk,
    const float* __restrict__ bv, unsigned short* __restrict__ oq,
    unsigned short* __restrict__ ok, unsigned short* __restrict__ ov,
    float qscale) {
  __shared__ unsigned short As[2 * 64 * 64];   // 16 KB
  __shared__ unsigned short Bs[2 * 128 * 64];  // 32 KB
  const int z = blockIdx.z;
  const unsigned short* A = z == 0 ? Aq : z == 1 ? Ak : Av;
  const unsigned short* Wt = z == 0 ? Wq : z == 1 ? Wk : Wv;
  const float* bias = z == 0 ? bq : z == 1 ? bk : bv;
  unsigned short* out = z == 0 ? oq : z == 1 ? ok : ov;
  const float scale = z == 0 ? qscale : 1.0f;
  const int m0 = blockIdx.x * 64, n0 = blockIdx.y * 128;
  const int tid = threadIdx.x, lane = tid & 63, w = tid >> 6;
  const int ln = lane & 15, lh = lane >> 4;
  const int wr = w >> 1, wc = w & 1;
  const int t0 = (blockIdx.x * 7 + blockIdx.y * 3 + blockIdx.z) & 15;
  f32x4 acc[2][4] = {};
  gemm_mainloop64((const char*)A, (const char*)Wt, (char*)As, (char*)Bs,
                  m0, n0, tid, t0, acc);
#pragma unroll
  for (int mi = 0; mi < 2; mi++) {
#pragma unroll
    for (int c = 0; c < 4; c++) {
      const int n = n0 + wc * 64 + c * 16 + ln;
      const float bv_ = bias[n];
      const int h = n >> 6, d = n & 63;
      const int mbase = m0 + wr * 32 + mi * 16 + lh * 4;
      if (z < 2) {
#pragma unroll
        for (int r = 0; r < 4; r++) {
          int m = mbase + r, b = m >> 11, s = m & (S_LEN - 1);
          out[((size_t)(b * NH + h) * S_LEN + s) * DEPTH + d] =
              b16((acc[mi][c][r] + bv_) * scale);
        }
      } else {  // V^T [B,H,d,S]
        const int b = mbase >> 11, s = mbase & (S_LEN - 1);
        us4 pk;
#pragma unroll
        for (int r = 0; r < 4; r++) pk[r] = b16(acc[mi][c][r] + bv_);
        *(us4*)&out[((size_t)(b * NH + h) * DEPTH + d) * S_LEN + s] = pk;
      }
    }
  }
}

// ------------- final projection GEMM: f32 out, 64x128 tile -----------------
// R17: grid (64,8) = 512 blocks = 2 blocks/CU resident, full overlap.
__global__ __launch_bounds__(256) void gemm_out_k(
    const unsigned short* __restrict__ A, const unsigned short* __restrict__ Wt,
    const float* __restrict__ bias, float* __restrict__ out) {
  __shared__ unsigned short As[2 * 64 * 64];   // 16 KB
  __shared__ unsigned short Bs[2 * 128 * 64];  // 32 KB
  const int m0 = blockIdx.x * 64, n0 = blockIdx.y * 128;
  const int tid = threadIdx.x, lane = tid & 63, w = tid >> 6;
  const int ln = lane & 15, lh = lane >> 4;
  const int wr = w >> 1, wc = w & 1;
  const int t0 = (blockIdx.x * 7 + blockIdx.y * 3) & 15;
  f32x4 acc[2][4] = {};
  gemm_mainloop64((const char*)A, (const char*)Wt, (char*)As, (char*)Bs,
                  m0, n0, tid, t0, acc);
#pragma unroll
  for (int mi = 0; mi < 2; mi++) {
#pragma unroll
    for (int c = 0; c < 4; c++) {
      const int n = n0 + wc * 64 + c * 16 + ln;
      const float bv_ = bias[n];
      const int mbase = m0 + wr * 32 + mi * 16 + lh * 4;
#pragma unroll
      for (int r = 0; r < 4; r++)
        out[(size_t)(mbase + r) * DM + n] = acc[mi][c][r] + bv_;
    }
  }
}

// ---------------- attention: swapped QK^T, two-pass softmax, dbuf K ---------
// Pass 2: per-block ROTATED key-tile order keyed by qt (R12: de-aliases the
// 8 KB row-stride weights stream across HBM channels; key must maximize phase
// diversity among co-resident blocks -- by-bh regressed). Normal stores (R13:
// nt bypasses L2 write-combining, +22us). Loop-end: s_waitcnt vmcnt(8) +
// s_barrier -- staging loads retire, weight stores stay in flight (R16, T4).
__global__ __launch_bounds__(256) void attn_k(const unsigned short* __restrict__ Qh,
    const unsigned short* __restrict__ Kh, const unsigned short* __restrict__ Vt,
    float* __restrict__ Wout, unsigned short* __restrict__ attnOut) {
  __shared__ unsigned short Ks[2 * 128 * 64];  // 32 KB, dbuf swizzled linear
  char* KsB = (char*)Ks;
  const int flat = blockIdx.x;
  const int xcd = flat & 7, g = flat >> 3;
  const int qt = g & 31;
  const int bh = xcd + 8 * (g >> 5);
  const int tid = threadIdx.x, w = tid >> 6, lane = tid & 63;
  const int ln = lane & 15, lh = lane >> 4;
  const int q0 = qt * 64;
  const unsigned short* Qb = Qh + (size_t)bh * S_LEN * DEPTH;
  const char* KbB = (const char*)(Kh + (size_t)bh * S_LEN * DEPTH);
  const unsigned short* Vb = Vt + (size_t)bh * DEPTH * S_LEN;
  // Q fragment (B-operand): n = q-row = ln, k = depth
  const int qrow = q0 + w * 16 + ln;
  const us8 qf0 = *(const us8*)(Qb + (size_t)qrow * DEPTH + lh * 8);
  const us8 qf1 = *(const us8*)(Qb + (size_t)qrow * DEPTH + 32 + lh * 8);

  // ---- pass 1: l = sum over keys of exp2(score') for q-row ln ----
  float l = 0.f;
  stage128k(KbB, 0, KsB, tid);
  __syncthreads();
  for (int t = 0; t < 16; t++) {
    const int cur = (t & 1) << 14, nxt = cur ^ (1 << 14);
    if (t < 15) stage128k(KbB, (t + 1) * 128, KsB + nxt, tid);
#pragma unroll
    for (int kt2 = 0; kt2 < 4; kt2++) {
      const int r0 = kt2 * 32 + ln;
      f32x4 d0 = {0.f, 0.f, 0.f, 0.f}, d1 = {0.f, 0.f, 0.f, 0.f};
      d0 = mfma16(SWZ_RD(KsB + cur, r0, lh), qf0, d0);
      d0 = mfma16(SWZ_RD(KsB + cur, r0, 4 + lh), qf1, d0);
      d1 = mfma16(SWZ_RD(KsB + cur, r0 + 16, lh), qf0, d1);
      d1 = mfma16(SWZ_RD(KsB + cur, r0 + 16, 4 + lh), qf1, d1);
      l += (ex2(d0[0]) + ex2(d0[1])) + (ex2(d0[2]) + ex2(d0[3])) +
           (ex2(d1[0]) + ex2(d1[1])) + (ex2(d1[2]) + ex2(d1[3]));
    }
    __syncthreads();
  }
  l += __shfl_xor(l, 16);
  l += __shfl_xor(l, 32);
  const float rl = 1.0f / l;

  // ---- pass 2: qt-rotated t-order; weights -> d_out, PV accumulate ----
  f32x4 o[4] = {};
  float* Wr = Wout + (size_t)bh * S_LEN * S_LEN + (size_t)(q0 + w * 16 + ln) * S_LEN;
  const int t0 = qt & 15;
  stage128k(KbB, t0 * 128, KsB, tid);
  __syncthreads();
  for (int i = 0; i < 16; i++) {
    const int t = (t0 + i) & 15;
    const int cur = (i & 1) << 14, nxt = cur ^ (1 << 14);
    if (i < 15) stage128k(KbB, ((t0 + i + 1) & 15) * 128, KsB + nxt, tid);
    __builtin_amdgcn_sched_barrier(0);  // staging loads issue first (oldest in vmcnt FIFO)
    const int sc = t * 128;
#pragma unroll
    for (int kt2 = 0; kt2 < 4; kt2++) {
      const int r0 = kt2 * 32 + ln;
      f32x4 d0 = {0.f, 0.f, 0.f, 0.f}, d1 = {0.f, 0.f, 0.f, 0.f};
      d0 = mfma16(SWZ_RD(KsB + cur, r0, lh), qf0, d0);
      d0 = mfma16(SWZ_RD(KsB + cur, r0, 4 + lh), qf1, d0);
      d1 = mfma16(SWZ_RD(KsB + cur, r0 + 16, lh), qf0, d1);
      d1 = mfma16(SWZ_RD(KsB + cur, r0 + 16, 4 + lh), qf1, d1);
      // lane owns q-row ln, keys sc + kt2*32 + 8*lh + {0..7}
      f32x4 w0, w1;
#pragma unroll
      for (int r = 0; r < 4; r++) {
        w0[r] = ex2(d0[r]) * rl;
        w1[r] = ex2(d1[r]) * rl;
      }
      *(f32x4*)(Wr + sc + kt2 * 32 + 8 * lh) = w0;
      *(f32x4*)(Wr + sc + kt2 * 32 + 8 * lh + 4) = w1;
      // bf16 pack IS the PV A-fragment (row ln, keys 8lh..8lh+7)
      us8 af;
      af[0] = b16(w0[0]); af[1] = b16(w0[1]);
      af[2] = b16(w0[2]); af[3] = b16(w0[3]);
      af[4] = b16(w1[0]); af[5] = b16(w1[1]);
      af[6] = b16(w1[2]); af[7] = b16(w1[3]);
#pragma unroll
      for (int dt = 0; dt < 4; dt++) {
        us8 vf = *(const us8*)(Vb + (size_t)(dt * 16 + ln) * S_LEN + sc +
                               kt2 * 32 + lh * 8);
        o[dt] = mfma16(af, vf, o[dt]);
      }
    }
    // staging (oldest 4 VMEM ops) retired; up to 8 weight stores stay in flight
    asm volatile("s_waitcnt vmcnt(8)" ::: "memory");
    __builtin_amdgcn_s_barrier();
  }

  const int b = bh >> 4, h = bh & 15;
#pragma unroll
  for (int dt = 0; dt < 4; dt++) {
#pragma unroll
    for (int r = 0; r < 4; r++) {
      size_t row = (size_t)b * S_LEN + q0 + w * 16 + lh * 4 + r;
      attnOut[row * DM + h * DEPTH + dt * 16 + ln] = b16(o[dt][r]);
    }
  }
}

extern "C" void kernel_launch(void* const* d_in, const int* in_sizes, int n_in,
                              void* d_out, int out_size, void* d_ws, size_t ws_size,
                              hipStream_t stream) {
  const float* queries = (const float*)d_in[0];
  const float* keys    = (const float*)d_in[1];
  const float* values  = (const float*)d_in[2];
  const float* wq = (const float*)d_in[3];
  const float* bq = (const float*)d_in[4];
  const float* wk = (const float*)d_in[5];
  const float* bk = (const float*)d_in[6];
  const float* wv = (const float*)d_in[7];
  const float* bv = (const float*)d_in[8];
  const float* wo = (const float*)d_in[9];
  const float* bo = (const float*)d_in[10];

  float* out = (float*)d_out;
  float* wts = out + (size_t)BATCH * S_LEN * DM;  // weights output after `out`

  char* ws = (char*)d_ws;
  const size_t WSZ = (size_t)DM * DM * sizeof(unsigned short);            // 2 MB
  const size_t TSZ = (size_t)BATCH * S_LEN * DM * sizeof(unsigned short); // 8 MB
  unsigned short* Wqt = (unsigned short*)(ws + 0 * WSZ);
  unsigned short* Wkt = (unsigned short*)(ws + 1 * WSZ);
  unsigned short* Wvt = (unsigned short*)(ws + 2 * WSZ);
  unsigned short* Wot = (unsigned short*)(ws + 3 * WSZ);
  unsigned short* Qbf = (unsigned short*)(ws + 4 * WSZ + 0 * TSZ);
  unsigned short* Kbf = (unsigned short*)(ws + 4 * WSZ + 1 * TSZ);
  unsigned short* Vbf = (unsigned short*)(ws + 4 * WSZ + 2 * TSZ);
  unsigned short* Qhd = (unsigned short*)(ws + 4 * WSZ + 3 * TSZ);
  unsigned short* Khd = (unsigned short*)(ws + 4 * WSZ + 4 * TSZ);
  unsigned short* Vtd = (unsigned short*)(ws + 4 * WSZ + 5 * TSZ);
  unsigned short* attn = Qbf;  // Qbf dead after Q-projection; reuse for attn out

  prep_k<<<dim3(2048, 7), 256, 0, stream>>>(queries, keys, values,
                                            Qbf, Kbf, Vbf,
                                            wq, wk, wv, wo,
                                            Wqt, Wkt, Wvt, Wot);
  gemm_qkv_k<<<dim3(64, 8, 3), 256, 0, stream>>>(Qbf, Kbf, Vbf, Wqt, Wkt, Wvt,
                                                 bq, bk, bv, Qhd, Khd, Vtd,
                                                 0.125f * LOG2E);
  attn_k<<<1024, 256, 0, stream>>>(Qhd, Khd, Vtd, wts, attn);
  gemm_out_k<<<dim3(64, 8), 256, 0, stream>>>(attn, Wot, bo, out);
}